// Round 2
// baseline (1736.173 us; speedup 1.0000x reference)
//
#include <hip/hip_runtime.h>

#define NN 100000
#define NE 3200000
#define DD 256
#define NT 8192
#define NOUT 10

typedef unsigned short u16;
typedef __attribute__((ext_vector_type(8))) short bf16x8;
typedef __attribute__((ext_vector_type(4))) float f32x4;

__device__ __forceinline__ float bf2f(u16 u) {
    union { unsigned int i; float f; } v; v.i = ((unsigned int)u) << 16; return v.f;
}
__device__ __forceinline__ u16 f2bf(float f) {
    union { float f; unsigned int i; } v; v.f = f;
    unsigned int x = v.i;
    return (u16)((x + 0x7fffu + ((x >> 16) & 1u)) >> 16);
}

// ---- weight convert + transpose: Wt[l][n][k] = bf16(W[l][k][n]) ----
__global__ __launch_bounds__(256) void k_wt(const float* __restrict__ gW,
                                            const float* __restrict__ lW,
                                            u16* __restrict__ Wt) {
    int idx = blockIdx.x * 256 + threadIdx.x;      // < 6*65536
    int l = idx >> 16;
    int nk = idx & 65535;
    int n = nk >> 8, k = nk & 255;
    float v = (l < 4) ? gW[l * 65536 + k * 256 + n]
                      : lW[(l - 4) * 65536 + k * 256 + n];
    Wt[idx] = f2bf(v);
}

// ---- embedding gather -> bf16 x : one wave per node, float4 loads ----
__global__ __launch_bounds__(256) void k_embed(const int* __restrict__ tokens,
                                               const float* __restrict__ emb,
                                               u16* __restrict__ x) {
    int wave = threadIdx.x >> 6, lane = threadIdx.x & 63;
    int n = blockIdx.x * 4 + wave;
    int t = tokens[n];
    float4 v = *(const float4*)(emb + t * 256 + lane * 4);
    ushort4 o;
    o.x = f2bf(v.x); o.y = f2bf(v.y); o.z = f2bf(v.z); o.w = f2bf(v.w);
    *(ushort4*)(x + n * 256 + lane * 4) = o;
}

__global__ __launch_bounds__(256) void k_zero(int* __restrict__ p, int n) {
    int i = blockIdx.x * 256 + threadIdx.x;
    if (i < n) p[i] = 0;
}

__global__ __launch_bounds__(256) void k_count(const int* __restrict__ dst,
                                               int* __restrict__ degE) {
    int e = blockIdx.x * 256 + threadIdx.x;
    if (e < NE) atomicAdd(&degE[dst[e]], 1);
}

// ---- scan part A: per-block exclusive scan + block sums + dinv ----
__global__ __launch_bounds__(256) void k_scanA(const int* __restrict__ degE,
                                               int* __restrict__ csr_off,
                                               int* __restrict__ blockSums,
                                               float* __restrict__ dinv) {
    __shared__ int s[256];
    int t = threadIdx.x;
    int idx = blockIdx.x * 256 + t;
    int v = (idx < NN) ? degE[idx] : 0;
    if (idx < NN) dinv[idx] = rsqrtf((float)(v + 1));   // deg includes self loop
    s[t] = v;
    __syncthreads();
    for (int o = 1; o < 256; o <<= 1) {
        int add = (t >= o) ? s[t - o] : 0;
        __syncthreads();
        s[t] += add;
        __syncthreads();
    }
    if (idx < NN) csr_off[idx] = s[t] - v;   // block-local exclusive
    if (t == 255) blockSums[blockIdx.x] = s[255];
}

__global__ __launch_bounds__(512) void k_scanB(int* __restrict__ blockSums) {
    __shared__ int s[512];
    int t = threadIdx.x;
    int v = (t < 391) ? blockSums[t] : 0;
    s[t] = v;
    __syncthreads();
    for (int o = 1; o < 512; o <<= 1) {
        int add = (t >= o) ? s[t - o] : 0;
        __syncthreads();
        s[t] += add;
        __syncthreads();
    }
    if (t < 391) blockSums[t] = s[t] - v;    // exclusive
}

__global__ __launch_bounds__(256) void k_scanC(int* __restrict__ csr_off,
                                               const int* __restrict__ blockSums,
                                               int* __restrict__ cur) {
    int idx = blockIdx.x * 256 + threadIdx.x;
    if (idx < NN) {
        int o = csr_off[idx] + blockSums[blockIdx.x];
        csr_off[idx] = o;
        cur[idx] = o;
    }
    if (idx == 0) csr_off[NN] = NE;
}

// ---- scatter: only the src index (4 B/edge) — w recomputed in aggr ----
__global__ __launch_bounds__(256) void k_scatter(const int* __restrict__ src,
                                                 const int* __restrict__ dst,
                                                 int* __restrict__ cur,
                                                 int* __restrict__ csr_src) {
    int e = blockIdx.x * 256 + threadIdx.x;
    if (e >= NE) return;
    int s_ = src[e], d_ = dst[e];
    int pos = atomicAdd(&cur[d_], 1);
    csr_src[pos] = s_;
}

// ---- bf16 MFMA GEMM: C[M,256] = A[M,256] @ Bt^T (Bt is [256 n][256 k]) ----
__global__ __launch_bounds__(256) void k_gemm(const u16* __restrict__ A,
                                              const u16* __restrict__ Bt,
                                              u16* __restrict__ C, int M) {
    __shared__ u16 As[128 * 32];
    __shared__ u16 Bs[128 * 32];
    const int tid = threadIdx.x;
    const int wave = tid >> 6, lane = tid & 63;
    const int wm = wave >> 1, wn = wave & 1;
    const int rowBase = blockIdx.x * 128;
    const int colBase = blockIdx.y * 128;
    const int quad = lane >> 4, l16 = lane & 15;

    f32x4 acc[4][4] = {};

    for (int k0 = 0; k0 < 256; k0 += 32) {
        for (int c = tid; c < 512; c += 256) {
            int r = c >> 2, kc = c & 3;
            int grow = rowBase + r;
            if (grow >= M) grow = M - 1;
            uint4 v = *(const uint4*)(A + grow * 256 + k0 + kc * 8);
            int p = kc ^ (r & 3);
            *(uint4*)(As + r * 32 + p * 8) = v;
        }
        for (int c = tid; c < 512; c += 256) {
            int r = c >> 2, kc = c & 3;
            uint4 v = *(const uint4*)(Bt + (colBase + r) * 256 + k0 + kc * 8);
            int p = kc ^ (r & 3);
            *(uint4*)(Bs + r * 32 + p * 8) = v;
        }
        __syncthreads();
        bf16x8 a_frag[4], b_frag[4];
        for (int i = 0; i < 4; i++) {
            int r = wm * 64 + i * 16 + l16;
            int p = quad ^ (r & 3);
            a_frag[i] = *(const bf16x8*)(As + r * 32 + p * 8);
        }
        for (int j = 0; j < 4; j++) {
            int r = wn * 64 + j * 16 + l16;
            int p = quad ^ (r & 3);
            b_frag[j] = *(const bf16x8*)(Bs + r * 32 + p * 8);
        }
        for (int i = 0; i < 4; i++)
            for (int j = 0; j < 4; j++)
                acc[i][j] = __builtin_amdgcn_mfma_f32_16x16x32_bf16(
                    a_frag[i], b_frag[j], acc[i][j], 0, 0, 0);
        __syncthreads();
    }
    for (int i = 0; i < 4; i++)
        for (int j = 0; j < 4; j++) {
            int col = colBase + wn * 64 + j * 16 + l16;
            for (int r = 0; r < 4; r++) {
                int row = rowBase + wm * 64 + i * 16 + quad * 4 + r;
                if (row < M) C[row * 256 + col] = f2bf(acc[i][j][r]);
            }
        }
}

// ---- fused aggregate (self loop + CSR edges) + bias + LN + ReLU ----
__global__ __launch_bounds__(256) void k_aggr(const u16* __restrict__ h,
                                              const int* __restrict__ csr_off,
                                              const int* __restrict__ csr_src,
                                              const float* __restrict__ dinv,
                                              const float* __restrict__ bias,
                                              const float* __restrict__ gamma,
                                              const float* __restrict__ beta,
                                              u16* __restrict__ xo) {
    int wave = threadIdx.x >> 6, lane = threadIdx.x & 63;
    int node = blockIdx.x * 4 + wave;
    float dn = dinv[node];
    int base = node * 256 + lane * 4;
    ushort4 hv = *(const ushort4*)(h + base);
    float w0 = dn * dn;
    float a0 = w0 * bf2f(hv.x), a1 = w0 * bf2f(hv.y);
    float a2 = w0 * bf2f(hv.z), a3 = w0 * bf2f(hv.w);
    int beg = csr_off[node], end = csr_off[node + 1];
    int e = beg;
    for (; e + 4 <= end; e += 4) {
        int s0 = csr_src[e + 0], s1 = csr_src[e + 1];
        int s2 = csr_src[e + 2], s3 = csr_src[e + 3];
        float we0 = dinv[s0] * dn, we1 = dinv[s1] * dn;
        float we2 = dinv[s2] * dn, we3 = dinv[s3] * dn;
        ushort4 v0 = *(const ushort4*)(h + s0 * 256 + lane * 4);
        ushort4 v1 = *(const ushort4*)(h + s1 * 256 + lane * 4);
        ushort4 v2 = *(const ushort4*)(h + s2 * 256 + lane * 4);
        ushort4 v3 = *(const ushort4*)(h + s3 * 256 + lane * 4);
        a0 = fmaf(we0, bf2f(v0.x), a0); a1 = fmaf(we0, bf2f(v0.y), a1);
        a2 = fmaf(we0, bf2f(v0.z), a2); a3 = fmaf(we0, bf2f(v0.w), a3);
        a0 = fmaf(we1, bf2f(v1.x), a0); a1 = fmaf(we1, bf2f(v1.y), a1);
        a2 = fmaf(we1, bf2f(v1.z), a2); a3 = fmaf(we1, bf2f(v1.w), a3);
        a0 = fmaf(we2, bf2f(v2.x), a0); a1 = fmaf(we2, bf2f(v2.y), a1);
        a2 = fmaf(we2, bf2f(v2.z), a2); a3 = fmaf(we2, bf2f(v2.w), a3);
        a0 = fmaf(we3, bf2f(v3.x), a0); a1 = fmaf(we3, bf2f(v3.y), a1);
        a2 = fmaf(we3, bf2f(v3.z), a2); a3 = fmaf(we3, bf2f(v3.w), a3);
    }
    for (; e < end; ++e) {
        int s = csr_src[e];
        float w = dinv[s] * dn;
        ushort4 v = *(const ushort4*)(h + s * 256 + lane * 4);
        a0 = fmaf(w, bf2f(v.x), a0); a1 = fmaf(w, bf2f(v.y), a1);
        a2 = fmaf(w, bf2f(v.z), a2); a3 = fmaf(w, bf2f(v.w), a3);
    }
    float4 bv = *(const float4*)(bias + lane * 4);
    a0 += bv.x; a1 += bv.y; a2 += bv.z; a3 += bv.w;
    float s1 = a0 + a1 + a2 + a3;
    float s2 = a0 * a0 + a1 * a1 + a2 * a2 + a3 * a3;
    for (int o = 32; o >= 1; o >>= 1) {
        s1 += __shfl_xor(s1, o, 64);
        s2 += __shfl_xor(s2, o, 64);
    }
    float mean = s1 * (1.0f / 256.0f);
    float var = s2 * (1.0f / 256.0f) - mean * mean;
    float rstd = rsqrtf(var + 1e-5f);
    float4 gv = *(const float4*)(gamma + lane * 4);
    float4 be = *(const float4*)(beta + lane * 4);
    float y0 = fmaxf((a0 - mean) * rstd * gv.x + be.x, 0.0f);
    float y1 = fmaxf((a1 - mean) * rstd * gv.y + be.y, 0.0f);
    float y2 = fmaxf((a2 - mean) * rstd * gv.z + be.z, 0.0f);
    float y3 = fmaxf((a3 - mean) * rstd * gv.w + be.w, 0.0f);
    ushort4 o4;
    o4.x = f2bf(y0); o4.y = f2bf(y1); o4.z = f2bf(y2); o4.w = f2bf(y3);
    *(ushort4*)(xo + base) = o4;
}

__global__ __launch_bounds__(256) void k_gather(const u16* __restrict__ x,
                                                const int* __restrict__ tgt,
                                                u16* __restrict__ xt) {
    int wave = threadIdx.x >> 6, lane = threadIdx.x & 63;
    int row = blockIdx.x * 4 + wave;
    int t = tgt[row];
    *(ushort4*)(xt + row * 256 + lane * 4) =
        *(const ushort4*)(x + t * 256 + lane * 4);
}

__global__ __launch_bounds__(256) void k_lnrelu(const u16* __restrict__ h,
                                                const float* __restrict__ bias,
                                                const float* __restrict__ gamma,
                                                const float* __restrict__ beta,
                                                u16* __restrict__ xo) {
    int wave = threadIdx.x >> 6, lane = threadIdx.x & 63;
    int row = blockIdx.x * 4 + wave;
    int base = row * 256 + lane * 4;
    ushort4 hv = *(const ushort4*)(h + base);
    float4 bv = *(const float4*)(bias + lane * 4);
    float a0 = bf2f(hv.x) + bv.x, a1 = bf2f(hv.y) + bv.y;
    float a2 = bf2f(hv.z) + bv.z, a3 = bf2f(hv.w) + bv.w;
    float s1 = a0 + a1 + a2 + a3;
    float s2 = a0 * a0 + a1 * a1 + a2 * a2 + a3 * a3;
    for (int o = 32; o >= 1; o >>= 1) {
        s1 += __shfl_xor(s1, o, 64);
        s2 += __shfl_xor(s2, o, 64);
    }
    float mean = s1 * (1.0f / 256.0f);
    float var = s2 * (1.0f / 256.0f) - mean * mean;
    float rstd = rsqrtf(var + 1e-5f);
    float4 gv = *(const float4*)(gamma + lane * 4);
    float4 be = *(const float4*)(beta + lane * 4);
    float y0 = fmaxf((a0 - mean) * rstd * gv.x + be.x, 0.0f);
    float y1 = fmaxf((a1 - mean) * rstd * gv.y + be.y, 0.0f);
    float y2 = fmaxf((a2 - mean) * rstd * gv.z + be.z, 0.0f);
    float y3 = fmaxf((a3 - mean) * rstd * gv.w + be.w, 0.0f);
    ushort4 o4;
    o4.x = f2bf(y0); o4.y = f2bf(y1); o4.z = f2bf(y2); o4.w = f2bf(y3);
    *(ushort4*)(xo + base) = o4;
}

__global__ __launch_bounds__(256) void k_out(const u16* __restrict__ x,
                                             const float* __restrict__ W,
                                             const float* __restrict__ b,
                                             float* __restrict__ out) {
    int wave = threadIdx.x >> 6, lane = threadIdx.x & 63;
    int row = blockIdx.x * 4 + wave;
    ushort4 v = *(const ushort4*)(x + row * 256 + lane * 4);
    float x0 = bf2f(v.x), x1 = bf2f(v.y), x2 = bf2f(v.z), x3 = bf2f(v.w);
    int d = lane * 4;
    for (int o = 0; o < NOUT; o++) {
        float p = x0 * W[(d + 0) * NOUT + o] + x1 * W[(d + 1) * NOUT + o] +
                  x2 * W[(d + 2) * NOUT + o] + x3 * W[(d + 3) * NOUT + o];
        for (int off = 32; off >= 1; off >>= 1) p += __shfl_xor(p, off, 64);
        if (lane == 0) out[row * NOUT + o] = p + b[o];
    }
}

extern "C" void kernel_launch(void* const* d_in, const int* in_sizes, int n_in,
                              void* d_out, int out_size, void* d_ws, size_t ws_size,
                              hipStream_t stream) {
    (void)in_sizes; (void)n_in; (void)out_size; (void)ws_size;
    const int* tokens = (const int*)d_in[0];
    const int* edges = (const int*)d_in[1];
    const int* tgt = (const int*)d_in[2];
    const float* emb = (const float*)d_in[3];
    const float* gnn_W = (const float*)d_in[4];
    const float* gnn_b = (const float*)d_in[5];
    const float* gnn_g = (const float*)d_in[6];
    const float* gnn_be = (const float*)d_in[7];
    const float* lin_W = (const float*)d_in[8];
    const float* lin_b = (const float*)d_in[9];
    const float* lin_g = (const float*)d_in[10];
    const float* lin_be = (const float*)d_in[11];
    const float* out_W = (const float*)d_in[12];
    const float* out_b = (const float*)d_in[13];
    float* out = (float*)d_out;

    char* ws = (char*)d_ws;
    u16* x = (u16*)ws;           ws += (size_t)NN * 256 * 2;
    u16* h = (u16*)ws;           ws += (size_t)NN * 256 * 2;
    int* csr_src = (int*)ws;     ws += (size_t)NE * 4;
    int* degE = (int*)ws;        ws += (size_t)NN * 4;
    float* dinv = (float*)ws;    ws += (size_t)NN * 4;
    int* csr_off = (int*)ws;     ws += (size_t)(NN + 4) * 4;
    int* cur = (int*)ws;         ws += (size_t)NN * 4;
    int* blockSums = (int*)ws;   ws += 512 * 4;
    u16* Wt = (u16*)ws;          ws += (size_t)6 * 65536 * 2;
    u16* xt = (u16*)ws;          ws += (size_t)NT * 256 * 2;
    u16* ht = (u16*)ws;          ws += (size_t)NT * 256 * 2;

    const int* e_src = edges;
    const int* e_dst = edges + NE;

    k_wt<<<1536, 256, 0, stream>>>(gnn_W, lin_W, Wt);
    k_embed<<<25000, 256, 0, stream>>>(tokens, emb, x);
    k_zero<<<391, 256, 0, stream>>>(degE, NN);
    k_count<<<12500, 256, 0, stream>>>(e_dst, degE);
    k_scanA<<<391, 256, 0, stream>>>(degE, csr_off, blockSums, dinv);
    k_scanB<<<1, 512, 0, stream>>>(blockSums);
    k_scanC<<<391, 256, 0, stream>>>(csr_off, blockSums, cur);
    k_scatter<<<12500, 256, 0, stream>>>(e_src, e_dst, cur, csr_src);

    for (int l = 0; l < 4; l++) {
        k_gemm<<<dim3(782, 2), 256, 0, stream>>>(x, Wt + l * 65536, h, NN);
        k_aggr<<<25000, 256, 0, stream>>>(h, csr_off, csr_src, dinv,
                                          gnn_b + l * 256, gnn_g + l * 256,
                                          gnn_be + l * 256, x);
    }
    k_gather<<<2048, 256, 0, stream>>>(x, tgt, xt);
    for (int l = 0; l < 2; l++) {
        k_gemm<<<dim3(64, 2), 256, 0, stream>>>(xt, Wt + (4 + l) * 65536, ht, NT);
        k_lnrelu<<<2048, 256, 0, stream>>>(ht, lin_b + l * 256, lin_g + l * 256,
                                           lin_be + l * 256, xt);
    }
    k_out<<<2048, 256, 0, stream>>>(xt, out_W, out_b, out);
}

// Round 4
// 1445.170 us; speedup vs baseline: 1.2014x; 1.2014x over previous
//
#include <hip/hip_runtime.h>

#define NN 100000
#define NE 3200000
#define DD 256
#define NT 8192
#define NOUT 10
#define NBUCK 196        // ceil(100000/512) buckets of 512 dst nodes

typedef unsigned short u16;
typedef __attribute__((ext_vector_type(8))) short bf16x8;
typedef __attribute__((ext_vector_type(4))) float f32x4;

__device__ __forceinline__ float bf2f(u16 u) {
    union { unsigned int i; float f; } v; v.i = ((unsigned int)u) << 16; return v.f;
}
__device__ __forceinline__ u16 f2bf(float f) {
    union { float f; unsigned int i; } v; v.f = f;
    unsigned int x = v.i;
    return (u16)((x + 0x7fffu + ((x >> 16) & 1u)) >> 16);
}

// ---- weight convert + transpose: Wt[l][n][k] = bf16(W[l][k][n]) ----
__global__ __launch_bounds__(256) void k_wt(const float* __restrict__ gW,
                                            const float* __restrict__ lW,
                                            u16* __restrict__ Wt) {
    int idx = blockIdx.x * 256 + threadIdx.x;      // < 6*65536
    int l = idx >> 16;
    int nk = idx & 65535;
    int n = nk >> 8, k = nk & 255;
    float v = (l < 4) ? gW[l * 65536 + k * 256 + n]
                      : lW[(l - 4) * 65536 + k * 256 + n];
    Wt[idx] = f2bf(v);
}

// ---- embedding gather -> bf16 x : one wave per node, float4 loads ----
__global__ __launch_bounds__(256) void k_embed(const int* __restrict__ tokens,
                                               const float* __restrict__ emb,
                                               u16* __restrict__ x) {
    int wave = threadIdx.x >> 6, lane = threadIdx.x & 63;
    int n = blockIdx.x * 4 + wave;
    int t = tokens[n];
    float4 v = *(const float4*)(emb + t * 256 + lane * 4);
    ushort4 o;
    o.x = f2bf(v.x); o.y = f2bf(v.y); o.z = f2bf(v.z); o.w = f2bf(v.w);
    *(ushort4*)(x + n * 256 + lane * 4) = o;
}

__global__ __launch_bounds__(256) void k_zero(int* __restrict__ p, int n) {
    int i = blockIdx.x * 256 + threadIdx.x;
    if (i < n) p[i] = 0;
}

// ---- pass A: per-bucket edge counts ----
__global__ __launch_bounds__(256) void k_binA(const int* __restrict__ dst,
                                              int* __restrict__ bucketCnt) {
    __shared__ int hist[NBUCK];
    int t = threadIdx.x;
    if (t < NBUCK) hist[t] = 0;
    __syncthreads();
    int base = blockIdx.x * 4096;
#pragma unroll
    for (int i = 0; i < 16; i++) {
        int e = base + i * 256 + t;
        if (e < NE) atomicAdd(&hist[dst[e] >> 9], 1);
    }
    __syncthreads();
    if (t < NBUCK && hist[t] > 0) atomicAdd(&bucketCnt[t], hist[t]);
}

// ---- scan bucket counts -> bucketOff (stable) + bucketCur (cursor) ----
__global__ __launch_bounds__(256) void k_bscan(const int* __restrict__ bucketCnt,
                                               int* __restrict__ bucketOff,
                                               int* __restrict__ bucketCur) {
    __shared__ int s[256];
    int t = threadIdx.x;
    int v = (t < NBUCK) ? bucketCnt[t] : 0;
    s[t] = v;
    __syncthreads();
    for (int o = 1; o < 256; o <<= 1) {
        int a = (t >= o) ? s[t - o] : 0;
        __syncthreads();
        s[t] += a;
        __syncthreads();
    }
    if (t < NBUCK) {
        int ex = s[t] - v;
        bucketOff[t] = ex;
        bucketCur[t] = ex;
    }
    if (t == 0) bucketOff[NBUCK] = NE;
}

// ---- pass B: write records at ABSOLUTE bucket offsets ----
// record = (src << 9) | (dst & 511)   (src < 2^17)
__global__ __launch_bounds__(256) void k_binB(const int* __restrict__ src,
                                              const int* __restrict__ dst,
                                              int* __restrict__ bucketCur,
                                              int* __restrict__ recs) {
    __shared__ int hist[NBUCK];
    __shared__ int gbase[NBUCK];
    int t = threadIdx.x;
    if (t < NBUCK) hist[t] = 0;
    __syncthreads();
    int base = blockIdx.x * 4096;
    int recv[16], bks[16], rnk[16];
#pragma unroll
    for (int i = 0; i < 16; i++) {
        int e = base + i * 256 + t;
        int bk = -1, rec = 0;
        if (e < NE) {
            int s_ = src[e], d_ = dst[e];
            bk = d_ >> 9;
            rec = (s_ << 9) | (d_ & 511);
        }
        bks[i] = bk; recv[i] = rec;
    }
#pragma unroll
    for (int i = 0; i < 16; i++)
        rnk[i] = (bks[i] >= 0) ? atomicAdd(&hist[bks[i]], 1) : 0;
    __syncthreads();
    if (t < NBUCK) {
        int c = hist[t];
        gbase[t] = (c > 0) ? atomicAdd(&bucketCur[t], c) : 0;  // absolute now
    }
    __syncthreads();
#pragma unroll
    for (int i = 0; i < 16; i++)
        if (bks[i] >= 0) {
            int pos = gbase[bks[i]] + rnk[i];
            pos = min(max(pos, 0), NE - 1);
            recs[pos] = recv[i];
        }
}

// ---- per-bucket CSR finalize (64KB L2-resident scatter window) ----
__global__ __launch_bounds__(256) void k_csr(const int* __restrict__ recs,
                                             const int* __restrict__ bucketOff,
                                             int* __restrict__ csr_src,
                                             int* __restrict__ csr_off,
                                             float* __restrict__ dinv) {
    __shared__ int cnt[512], off[512], cur[512];
    int b = blockIdx.x, t = threadIdx.x;
    int beg = min(max(bucketOff[b], 0), NE);
    int end = min(max(bucketOff[b + 1], beg), NE);
    int n = end - beg;
    cnt[t] = 0; cnt[t + 256] = 0;
    cur[t] = 0; cur[t + 256] = 0;
    __syncthreads();
    for (int i = t; i < n; i += 256)
        atomicAdd(&cnt[recs[beg + i] & 511], 1);
    __syncthreads();
    off[t] = cnt[t]; off[t + 256] = cnt[t + 256];
    __syncthreads();
    for (int o = 1; o < 512; o <<= 1) {
        int v0 = (t >= o) ? off[t - o] : 0;
        int v1 = (t + 256 >= o) ? off[t + 256 - o] : 0;
        __syncthreads();
        off[t] += v0; off[t + 256] += v1;
        __syncthreads();
    }
    // off is inclusive scan; exclusive = off - cnt
    int nodeBase = b * 512;
    for (int k = t; k < 512; k += 256) {
        int node = nodeBase + k;
        if (node < NN) {
            csr_off[node] = beg + off[k] - cnt[k];
            dinv[node] = rsqrtf((float)(cnt[k] + 1));
        }
    }
    if (b == 0 && t == 0) csr_off[NN] = NE;
    __syncthreads();
    for (int i = t; i < n; i += 256) {
        int r = recs[beg + i];
        int dlow = r & 511;
        int rk = atomicAdd(&cur[dlow], 1);
        int pos = beg + off[dlow] - cnt[dlow] + rk;
        pos = min(max(pos, 0), NE - 1);
        csr_src[pos] = min(max(r >> 9, 0), NN - 1);
    }
}

// ---- bf16 MFMA GEMM: C[M,256] = A[M,256] @ Bt^T (Bt is [256 n][256 k]) ----
__global__ __launch_bounds__(256) void k_gemm(const u16* __restrict__ A,
                                              const u16* __restrict__ Bt,
                                              u16* __restrict__ C, int M) {
    __shared__ u16 As[128 * 32];
    __shared__ u16 Bs[128 * 32];
    const int tid = threadIdx.x;
    const int wave = tid >> 6, lane = tid & 63;
    const int wm = wave >> 1, wn = wave & 1;
    const int rowBase = blockIdx.x * 128;
    const int colBase = blockIdx.y * 128;
    const int quad = lane >> 4, l16 = lane & 15;

    f32x4 acc[4][4] = {};

    for (int k0 = 0; k0 < 256; k0 += 32) {
        for (int c = tid; c < 512; c += 256) {
            int r = c >> 2, kc = c & 3;
            int grow = rowBase + r;
            if (grow >= M) grow = M - 1;
            uint4 v = *(const uint4*)(A + grow * 256 + k0 + kc * 8);
            int p = kc ^ (r & 3);
            *(uint4*)(As + r * 32 + p * 8) = v;
        }
        for (int c = tid; c < 512; c += 256) {
            int r = c >> 2, kc = c & 3;
            uint4 v = *(const uint4*)(Bt + (colBase + r) * 256 + k0 + kc * 8);
            int p = kc ^ (r & 3);
            *(uint4*)(Bs + r * 32 + p * 8) = v;
        }
        __syncthreads();
        bf16x8 a_frag[4], b_frag[4];
        for (int i = 0; i < 4; i++) {
            int r = wm * 64 + i * 16 + l16;
            int p = quad ^ (r & 3);
            a_frag[i] = *(const bf16x8*)(As + r * 32 + p * 8);
        }
        for (int j = 0; j < 4; j++) {
            int r = wn * 64 + j * 16 + l16;
            int p = quad ^ (r & 3);
            b_frag[j] = *(const bf16x8*)(Bs + r * 32 + p * 8);
        }
        for (int i = 0; i < 4; i++)
            for (int j = 0; j < 4; j++)
                acc[i][j] = __builtin_amdgcn_mfma_f32_16x16x32_bf16(
                    a_frag[i], b_frag[j], acc[i][j], 0, 0, 0);
        __syncthreads();
    }
    for (int i = 0; i < 4; i++)
        for (int j = 0; j < 4; j++) {
            int col = colBase + wn * 64 + j * 16 + l16;
            for (int r = 0; r < 4; r++) {
                int row = rowBase + wm * 64 + i * 16 + quad * 4 + r;
                if (row < M) C[row * 256 + col] = f2bf(acc[i][j][r]);
            }
        }
}

// ---- fused aggregate (self loop + CSR edges) + bias + LN + ReLU ----
__global__ __launch_bounds__(256) void k_aggr(const u16* __restrict__ h,
                                              const int* __restrict__ csr_off,
                                              const int* __restrict__ csr_src,
                                              const float* __restrict__ dinv,
                                              const float* __restrict__ bias,
                                              const float* __restrict__ gamma,
                                              const float* __restrict__ beta,
                                              u16* __restrict__ xo) {
    int wave = threadIdx.x >> 6, lane = threadIdx.x & 63;
    int node = blockIdx.x * 4 + wave;
    float dn = dinv[node];
    int base = node * 256 + lane * 4;
    ushort4 hv = *(const ushort4*)(h + base);
    float w0 = dn * dn;
    float a0 = w0 * bf2f(hv.x), a1 = w0 * bf2f(hv.y);
    float a2 = w0 * bf2f(hv.z), a3 = w0 * bf2f(hv.w);
    int beg = min(max(csr_off[node], 0), NE);
    int end = min(max(csr_off[node + 1], beg), NE);
    int e = beg;
    for (; e + 4 <= end; e += 4) {
        int s0 = csr_src[e + 0], s1 = csr_src[e + 1];
        int s2 = csr_src[e + 2], s3 = csr_src[e + 3];
        float we0 = dinv[s0] * dn, we1 = dinv[s1] * dn;
        float we2 = dinv[s2] * dn, we3 = dinv[s3] * dn;
        ushort4 v0 = *(const ushort4*)(h + s0 * 256 + lane * 4);
        ushort4 v1 = *(const ushort4*)(h + s1 * 256 + lane * 4);
        ushort4 v2 = *(const ushort4*)(h + s2 * 256 + lane * 4);
        ushort4 v3 = *(const ushort4*)(h + s3 * 256 + lane * 4);
        a0 = fmaf(we0, bf2f(v0.x), a0); a1 = fmaf(we0, bf2f(v0.y), a1);
        a2 = fmaf(we0, bf2f(v0.z), a2); a3 = fmaf(we0, bf2f(v0.w), a3);
        a0 = fmaf(we1, bf2f(v1.x), a0); a1 = fmaf(we1, bf2f(v1.y), a1);
        a2 = fmaf(we1, bf2f(v1.z), a2); a3 = fmaf(we1, bf2f(v1.w), a3);
        a0 = fmaf(we2, bf2f(v2.x), a0); a1 = fmaf(we2, bf2f(v2.y), a1);
        a2 = fmaf(we2, bf2f(v2.z), a2); a3 = fmaf(we2, bf2f(v2.w), a3);
        a0 = fmaf(we3, bf2f(v3.x), a0); a1 = fmaf(we3, bf2f(v3.y), a1);
        a2 = fmaf(we3, bf2f(v3.z), a2); a3 = fmaf(we3, bf2f(v3.w), a3);
    }
    for (; e < end; ++e) {
        int s = csr_src[e];
        float w = dinv[s] * dn;
        ushort4 v = *(const ushort4*)(h + s * 256 + lane * 4);
        a0 = fmaf(w, bf2f(v.x), a0); a1 = fmaf(w, bf2f(v.y), a1);
        a2 = fmaf(w, bf2f(v.z), a2); a3 = fmaf(w, bf2f(v.w), a3);
    }
    float4 bv = *(const float4*)(bias + lane * 4);
    a0 += bv.x; a1 += bv.y; a2 += bv.z; a3 += bv.w;
    float s1 = a0 + a1 + a2 + a3;
    float s2 = a0 * a0 + a1 * a1 + a2 * a2 + a3 * a3;
    for (int o = 32; o >= 1; o >>= 1) {
        s1 += __shfl_xor(s1, o, 64);
        s2 += __shfl_xor(s2, o, 64);
    }
    float mean = s1 * (1.0f / 256.0f);
    float var = s2 * (1.0f / 256.0f) - mean * mean;
    float rstd = rsqrtf(var + 1e-5f);
    float4 gv = *(const float4*)(gamma + lane * 4);
    float4 be = *(const float4*)(beta + lane * 4);
    float y0 = fmaxf((a0 - mean) * rstd * gv.x + be.x, 0.0f);
    float y1 = fmaxf((a1 - mean) * rstd * gv.y + be.y, 0.0f);
    float y2 = fmaxf((a2 - mean) * rstd * gv.z + be.z, 0.0f);
    float y3 = fmaxf((a3 - mean) * rstd * gv.w + be.w, 0.0f);
    ushort4 o4;
    o4.x = f2bf(y0); o4.y = f2bf(y1); o4.z = f2bf(y2); o4.w = f2bf(y3);
    *(ushort4*)(xo + base) = o4;
}

__global__ __launch_bounds__(256) void k_gather(const u16* __restrict__ x,
                                                const int* __restrict__ tgt,
                                                u16* __restrict__ xt) {
    int wave = threadIdx.x >> 6, lane = threadIdx.x & 63;
    int row = blockIdx.x * 4 + wave;
    int t = tgt[row];
    *(ushort4*)(xt + row * 256 + lane * 4) =
        *(const ushort4*)(x + t * 256 + lane * 4);
}

__global__ __launch_bounds__(256) void k_lnrelu(const u16* __restrict__ h,
                                                const float* __restrict__ bias,
                                                const float* __restrict__ gamma,
                                                const float* __restrict__ beta,
                                                u16* __restrict__ xo) {
    int wave = threadIdx.x >> 6, lane = threadIdx.x & 63;
    int row = blockIdx.x * 4 + wave;
    int base = row * 256 + lane * 4;
    ushort4 hv = *(const ushort4*)(h + base);
    float4 bv = *(const float4*)(bias + lane * 4);
    float a0 = bf2f(hv.x) + bv.x, a1 = bf2f(hv.y) + bv.y;
    float a2 = bf2f(hv.z) + bv.z, a3 = bf2f(hv.w) + bv.w;
    float s1 = a0 + a1 + a2 + a3;
    float s2 = a0 * a0 + a1 * a1 + a2 * a2 + a3 * a3;
    for (int o = 32; o >= 1; o >>= 1) {
        s1 += __shfl_xor(s1, o, 64);
        s2 += __shfl_xor(s2, o, 64);
    }
    float mean = s1 * (1.0f / 256.0f);
    float var = s2 * (1.0f / 256.0f) - mean * mean;
    float rstd = rsqrtf(var + 1e-5f);
    float4 gv = *(const float4*)(gamma + lane * 4);
    float4 be = *(const float4*)(beta + lane * 4);
    float y0 = fmaxf((a0 - mean) * rstd * gv.x + be.x, 0.0f);
    float y1 = fmaxf((a1 - mean) * rstd * gv.y + be.y, 0.0f);
    float y2 = fmaxf((a2 - mean) * rstd * gv.z + be.z, 0.0f);
    float y3 = fmaxf((a3 - mean) * rstd * gv.w + be.w, 0.0f);
    ushort4 o4;
    o4.x = f2bf(y0); o4.y = f2bf(y1); o4.z = f2bf(y2); o4.w = f2bf(y3);
    *(ushort4*)(xo + base) = o4;
}

__global__ __launch_bounds__(256) void k_out(const u16* __restrict__ x,
                                             const float* __restrict__ W,
                                             const float* __restrict__ b,
                                             float* __restrict__ out) {
    int wave = threadIdx.x >> 6, lane = threadIdx.x & 63;
    int row = blockIdx.x * 4 + wave;
    ushort4 v = *(const ushort4*)(x + row * 256 + lane * 4);
    float x0 = bf2f(v.x), x1 = bf2f(v.y), x2 = bf2f(v.z), x3 = bf2f(v.w);
    int d = lane * 4;
    for (int o = 0; o < NOUT; o++) {
        float p = x0 * W[(d + 0) * NOUT + o] + x1 * W[(d + 1) * NOUT + o] +
                  x2 * W[(d + 2) * NOUT + o] + x3 * W[(d + 3) * NOUT + o];
        for (int off = 32; off >= 1; off >>= 1) p += __shfl_xor(p, off, 64);
        if (lane == 0) out[row * NOUT + o] = p + b[o];
    }
}

extern "C" void kernel_launch(void* const* d_in, const int* in_sizes, int n_in,
                              void* d_out, int out_size, void* d_ws, size_t ws_size,
                              hipStream_t stream) {
    (void)in_sizes; (void)n_in; (void)out_size; (void)ws_size;
    const int* tokens = (const int*)d_in[0];
    const int* edges = (const int*)d_in[1];
    const int* tgt = (const int*)d_in[2];
    const float* emb = (const float*)d_in[3];
    const float* gnn_W = (const float*)d_in[4];
    const float* gnn_b = (const float*)d_in[5];
    const float* gnn_g = (const float*)d_in[6];
    const float* gnn_be = (const float*)d_in[7];
    const float* lin_W = (const float*)d_in[8];
    const float* lin_b = (const float*)d_in[9];
    const float* lin_g = (const float*)d_in[10];
    const float* lin_be = (const float*)d_in[11];
    const float* out_W = (const float*)d_in[12];
    const float* out_b = (const float*)d_in[13];
    float* out = (float*)d_out;

    char* ws = (char*)d_ws;
    u16* x = (u16*)ws;           ws += (size_t)NN * 256 * 2;
    u16* h = (u16*)ws;           ws += (size_t)NN * 256 * 2;
    int* csr_src = (int*)ws;     ws += (size_t)NE * 4;
    int* recs = (int*)ws;        ws += (size_t)NE * 4;
    float* dinv = (float*)ws;    ws += (size_t)NN * 4;
    int* csr_off = (int*)ws;     ws += (size_t)(NN + 4) * 4;
    int* bucketCnt = (int*)ws;   ws += 256 * 4;
    int* bucketOff = (int*)ws;   ws += 256 * 4;
    int* bucketCur = (int*)ws;   ws += 256 * 4;
    u16* Wt = (u16*)ws;          ws += (size_t)6 * 65536 * 2;
    u16* xt = (u16*)ws;          ws += (size_t)NT * 256 * 2;
    u16* ht = (u16*)ws;          ws += (size_t)NT * 256 * 2;

    const int* e_src = edges;
    const int* e_dst = edges + NE;

    k_wt<<<1536, 256, 0, stream>>>(gnn_W, lin_W, Wt);
    k_embed<<<25000, 256, 0, stream>>>(tokens, emb, x);
    k_zero<<<1, 256, 0, stream>>>(bucketCnt, NBUCK);
    k_binA<<<782, 256, 0, stream>>>(e_dst, bucketCnt);
    k_bscan<<<1, 256, 0, stream>>>(bucketCnt, bucketOff, bucketCur);
    k_binB<<<782, 256, 0, stream>>>(e_src, e_dst, bucketCur, recs);
    k_csr<<<NBUCK, 256, 0, stream>>>(recs, bucketOff, csr_src, csr_off, dinv);

    for (int l = 0; l < 4; l++) {
        k_gemm<<<dim3(782, 2), 256, 0, stream>>>(x, Wt + l * 65536, h, NN);
        k_aggr<<<25000, 256, 0, stream>>>(h, csr_off, csr_src, dinv,
                                          gnn_b + l * 256, gnn_g + l * 256,
                                          gnn_be + l * 256, x);
    }
    k_gather<<<2048, 256, 0, stream>>>(x, tgt, xt);
    for (int l = 0; l < 2; l++) {
        k_gemm<<<dim3(64, 2), 256, 0, stream>>>(xt, Wt + (4 + l) * 65536, ht, NT);
        k_lnrelu<<<2048, 256, 0, stream>>>(ht, lin_b + l * 256, lin_g + l * 256,
                                           lin_be + l * 256, xt);
    }
    k_out<<<2048, 256, 0, stream>>>(xt, out_W, out_b, out);
}

// Round 5
// 1444.434 us; speedup vs baseline: 1.2020x; 1.0005x over previous
//
#include <hip/hip_runtime.h>

#define NN 100000
#define NE 3200000
#define DD 256
#define NT 8192
#define NOUT 10
#define NBUCK 196        // ceil(100000/512) buckets of 512 dst nodes

typedef unsigned short u16;
typedef __attribute__((ext_vector_type(8))) short bf16x8;
typedef __attribute__((ext_vector_type(4))) float f32x4;

__device__ __forceinline__ float bf2f(u16 u) {
    union { unsigned int i; float f; } v; v.i = ((unsigned int)u) << 16; return v.f;
}
__device__ __forceinline__ u16 f2bf(float f) {
    union { float f; unsigned int i; } v; v.f = f;
    unsigned int x = v.i;
    return (u16)((x + 0x7fffu + ((x >> 16) & 1u)) >> 16);
}
__device__ __forceinline__ unsigned int pack2(float a, float b) {
    return (unsigned int)f2bf(a) | ((unsigned int)f2bf(b) << 16);
}

#define UNPK(u, lo, hi) { union{unsigned int i; float f;} _x,_y; \
    _x.i=(u)<<16; _y.i=(u)&0xffff0000u; lo=_x.f; hi=_y.f; }

// ---- weight convert + transpose: Wt[l][n][k] = bf16(W[l][k][n]) ----
__global__ __launch_bounds__(256) void k_wt(const float* __restrict__ gW,
                                            const float* __restrict__ lW,
                                            u16* __restrict__ Wt) {
    int idx = blockIdx.x * 256 + threadIdx.x;      // < 6*65536
    int l = idx >> 16;
    int nk = idx & 65535;
    int n = nk >> 8, k = nk & 255;
    float v = (l < 4) ? gW[l * 65536 + k * 256 + n]
                      : lW[(l - 4) * 65536 + k * 256 + n];
    Wt[idx] = f2bf(v);
}

// ---- embedding gather -> bf16 x : one wave per node, float4 loads ----
__global__ __launch_bounds__(256) void k_embed(const int* __restrict__ tokens,
                                               const float* __restrict__ emb,
                                               u16* __restrict__ x) {
    int wave = threadIdx.x >> 6, lane = threadIdx.x & 63;
    int n = blockIdx.x * 4 + wave;
    int t = tokens[n];
    float4 v = *(const float4*)(emb + t * 256 + lane * 4);
    ushort4 o;
    o.x = f2bf(v.x); o.y = f2bf(v.y); o.z = f2bf(v.z); o.w = f2bf(v.w);
    *(ushort4*)(x + n * 256 + lane * 4) = o;
}

__global__ __launch_bounds__(256) void k_zero(int* __restrict__ p, int n) {
    int i = blockIdx.x * 256 + threadIdx.x;
    if (i < n) p[i] = 0;
}

// ---- pass A: per-bucket edge counts ----
__global__ __launch_bounds__(256) void k_binA(const int* __restrict__ dst,
                                              int* __restrict__ bucketCnt) {
    __shared__ int hist[NBUCK];
    int t = threadIdx.x;
    if (t < NBUCK) hist[t] = 0;
    __syncthreads();
    int base = blockIdx.x * 4096;
#pragma unroll
    for (int i = 0; i < 16; i++) {
        int e = base + i * 256 + t;
        if (e < NE) atomicAdd(&hist[dst[e] >> 9], 1);
    }
    __syncthreads();
    if (t < NBUCK && hist[t] > 0) atomicAdd(&bucketCnt[t], hist[t]);
}

// ---- scan bucket counts -> bucketOff (stable) + bucketCur (cursor) ----
__global__ __launch_bounds__(256) void k_bscan(const int* __restrict__ bucketCnt,
                                               int* __restrict__ bucketOff,
                                               int* __restrict__ bucketCur) {
    __shared__ int s[256];
    int t = threadIdx.x;
    int v = (t < NBUCK) ? bucketCnt[t] : 0;
    s[t] = v;
    __syncthreads();
    for (int o = 1; o < 256; o <<= 1) {
        int a = (t >= o) ? s[t - o] : 0;
        __syncthreads();
        s[t] += a;
        __syncthreads();
    }
    if (t < NBUCK) {
        int ex = s[t] - v;
        bucketOff[t] = ex;
        bucketCur[t] = ex;
    }
    if (t == 0) bucketOff[NBUCK] = NE;
}

// ---- pass B: write records at ABSOLUTE bucket offsets ----
// record = (src << 9) | (dst & 511)   (src < 2^17)
__global__ __launch_bounds__(256) void k_binB(const int* __restrict__ src,
                                              const int* __restrict__ dst,
                                              int* __restrict__ bucketCur,
                                              int* __restrict__ recs) {
    __shared__ int hist[NBUCK];
    __shared__ int gbase[NBUCK];
    int t = threadIdx.x;
    if (t < NBUCK) hist[t] = 0;
    __syncthreads();
    int base = blockIdx.x * 4096;
    int recv[16], bks[16], rnk[16];
#pragma unroll
    for (int i = 0; i < 16; i++) {
        int e = base + i * 256 + t;
        int bk = -1, rec = 0;
        if (e < NE) {
            int s_ = src[e], d_ = dst[e];
            bk = d_ >> 9;
            rec = (s_ << 9) | (d_ & 511);
        }
        bks[i] = bk; recv[i] = rec;
    }
#pragma unroll
    for (int i = 0; i < 16; i++)
        rnk[i] = (bks[i] >= 0) ? atomicAdd(&hist[bks[i]], 1) : 0;
    __syncthreads();
    if (t < NBUCK) {
        int c = hist[t];
        gbase[t] = (c > 0) ? atomicAdd(&bucketCur[t], c) : 0;  // absolute
    }
    __syncthreads();
#pragma unroll
    for (int i = 0; i < 16; i++)
        if (bks[i] >= 0) {
            int pos = gbase[bks[i]] + rnk[i];
            pos = min(max(pos, 0), NE - 1);
            recs[pos] = recv[i];
        }
}

// ---- per-bucket CSR finalize (64KB L2-resident scatter window) ----
__global__ __launch_bounds__(256) void k_csr(const int* __restrict__ recs,
                                             const int* __restrict__ bucketOff,
                                             int* __restrict__ csr_src,
                                             int* __restrict__ csr_off,
                                             float* __restrict__ dinv) {
    __shared__ int cnt[512], off[512], cur[512];
    int b = blockIdx.x, t = threadIdx.x;
    int beg = min(max(bucketOff[b], 0), NE);
    int end = min(max(bucketOff[b + 1], beg), NE);
    int n = end - beg;
    cnt[t] = 0; cnt[t + 256] = 0;
    cur[t] = 0; cur[t + 256] = 0;
    __syncthreads();
    for (int i = t; i < n; i += 256)
        atomicAdd(&cnt[recs[beg + i] & 511], 1);
    __syncthreads();
    off[t] = cnt[t]; off[t + 256] = cnt[t + 256];
    __syncthreads();
    for (int o = 1; o < 512; o <<= 1) {
        int v0 = (t >= o) ? off[t - o] : 0;
        int v1 = (t + 256 >= o) ? off[t + 256 - o] : 0;
        __syncthreads();
        off[t] += v0; off[t + 256] += v1;
        __syncthreads();
    }
    // off is inclusive scan; exclusive = off - cnt
    int nodeBase = b * 512;
    for (int k = t; k < 512; k += 256) {
        int node = nodeBase + k;
        if (node < NN) {
            csr_off[node] = beg + off[k] - cnt[k];
            dinv[node] = rsqrtf((float)(cnt[k] + 1));
        }
    }
    if (b == 0 && t == 0) csr_off[NN] = NE;
    __syncthreads();
    for (int i = t; i < n; i += 256) {
        int r = recs[beg + i];
        int dlow = r & 511;
        int rk = atomicAdd(&cur[dlow], 1);
        int pos = beg + off[dlow] - cnt[dlow] + rk;
        pos = min(max(pos, 0), NE - 1);
        csr_src[pos] = min(max(r >> 9, 0), NN - 1);
    }
}

// ---- bf16 MFMA GEMM: C[M,256] = A[M,256] @ Bt^T (Bt is [256 n][256 k]) ----
__global__ __launch_bounds__(256) void k_gemm(const u16* __restrict__ A,
                                              const u16* __restrict__ Bt,
                                              u16* __restrict__ C, int M) {
    __shared__ u16 As[128 * 32];
    __shared__ u16 Bs[128 * 32];
    const int tid = threadIdx.x;
    const int wave = tid >> 6, lane = tid & 63;
    const int wm = wave >> 1, wn = wave & 1;
    const int rowBase = blockIdx.x * 128;
    const int colBase = blockIdx.y * 128;
    const int quad = lane >> 4, l16 = lane & 15;

    f32x4 acc[4][4] = {};

    for (int k0 = 0; k0 < 256; k0 += 32) {
        for (int c = tid; c < 512; c += 256) {
            int r = c >> 2, kc = c & 3;
            int grow = rowBase + r;
            if (grow >= M) grow = M - 1;
            uint4 v = *(const uint4*)(A + grow * 256 + k0 + kc * 8);
            int p = kc ^ (r & 3);
            *(uint4*)(As + r * 32 + p * 8) = v;
        }
        for (int c = tid; c < 512; c += 256) {
            int r = c >> 2, kc = c & 3;
            uint4 v = *(const uint4*)(Bt + (colBase + r) * 256 + k0 + kc * 8);
            int p = kc ^ (r & 3);
            *(uint4*)(Bs + r * 32 + p * 8) = v;
        }
        __syncthreads();
        bf16x8 a_frag[4], b_frag[4];
        for (int i = 0; i < 4; i++) {
            int r = wm * 64 + i * 16 + l16;
            int p = quad ^ (r & 3);
            a_frag[i] = *(const bf16x8*)(As + r * 32 + p * 8);
        }
        for (int j = 0; j < 4; j++) {
            int r = wn * 64 + j * 16 + l16;
            int p = quad ^ (r & 3);
            b_frag[j] = *(const bf16x8*)(Bs + r * 32 + p * 8);
        }
        for (int i = 0; i < 4; i++)
            for (int j = 0; j < 4; j++)
                acc[i][j] = __builtin_amdgcn_mfma_f32_16x16x32_bf16(
                    a_frag[i], b_frag[j], acc[i][j], 0, 0, 0);
        __syncthreads();
    }
    for (int i = 0; i < 4; i++)
        for (int j = 0; j < 4; j++) {
            int col = colBase + wn * 64 + j * 16 + l16;
            for (int r = 0; r < 4; r++) {
                int row = rowBase + wm * 64 + i * 16 + quad * 4 + r;
                if (row < M) C[row * 256 + col] = f2bf(acc[i][j][r]);
            }
        }
}

// ---- fused aggregate + bias + LN + ReLU ----
// One node per wave; two 32-lane halves each cover the full 256-dim row at
// 16 B/lane and process 4 edges each -> 8 row-gathers in flight per wave.
__global__ __launch_bounds__(256) void k_aggr(const u16* __restrict__ h,
                                              const int* __restrict__ csr_off,
                                              const int* __restrict__ csr_src,
                                              const float* __restrict__ dinv,
                                              const float* __restrict__ bias,
                                              const float* __restrict__ gamma,
                                              const float* __restrict__ beta,
                                              u16* __restrict__ xo) {
    const int wave = threadIdx.x >> 6, lane = threadIdx.x & 63;
    const int half = lane >> 5, l32 = lane & 31;
    const int node = blockIdx.x * 4 + wave;
    const float dn = dinv[node];
    const int d8 = l32 * 8;                  // 8 dims per lane
    float a0,a1,a2,a3,a4,a5,a6,a7;
    {
        uint4 hv = *(const uint4*)(h + node * 256 + d8);
        float w0 = (half == 0) ? dn * dn : 0.0f;   // self loop counted once
        float p,q;
        UNPK(hv.x,p,q); a0 = w0*p; a1 = w0*q;
        UNPK(hv.y,p,q); a2 = w0*p; a3 = w0*q;
        UNPK(hv.z,p,q); a4 = w0*p; a5 = w0*q;
        UNPK(hv.w,p,q); a6 = w0*p; a7 = w0*q;
    }
    const int beg = csr_off[node], end = csr_off[node + 1];
    for (int e = beg + half * 4; e < end; e += 8) {
        int i1 = min(e + 1, end - 1);
        int i2 = min(e + 2, end - 1);
        int i3 = min(e + 3, end - 1);
        int s0 = csr_src[e];
        int s1 = csr_src[i1];
        int s2 = csr_src[i2];
        int s3 = csr_src[i3];
        uint4 v0 = *(const uint4*)(h + s0 * 256 + d8);
        uint4 v1 = *(const uint4*)(h + s1 * 256 + d8);
        uint4 v2 = *(const uint4*)(h + s2 * 256 + d8);
        uint4 v3 = *(const uint4*)(h + s3 * 256 + d8);
        float w0 = dinv[s0] * dn;
        float w1 = (e + 1 < end) ? dinv[s1] * dn : 0.0f;
        float w2 = (e + 2 < end) ? dinv[s2] * dn : 0.0f;
        float w3 = (e + 3 < end) ? dinv[s3] * dn : 0.0f;
        float p,q;
        UNPK(v0.x,p,q); a0=fmaf(w0,p,a0); a1=fmaf(w0,q,a1);
        UNPK(v0.y,p,q); a2=fmaf(w0,p,a2); a3=fmaf(w0,q,a3);
        UNPK(v0.z,p,q); a4=fmaf(w0,p,a4); a5=fmaf(w0,q,a5);
        UNPK(v0.w,p,q); a6=fmaf(w0,p,a6); a7=fmaf(w0,q,a7);
        UNPK(v1.x,p,q); a0=fmaf(w1,p,a0); a1=fmaf(w1,q,a1);
        UNPK(v1.y,p,q); a2=fmaf(w1,p,a2); a3=fmaf(w1,q,a3);
        UNPK(v1.z,p,q); a4=fmaf(w1,p,a4); a5=fmaf(w1,q,a5);
        UNPK(v1.w,p,q); a6=fmaf(w1,p,a6); a7=fmaf(w1,q,a7);
        UNPK(v2.x,p,q); a0=fmaf(w2,p,a0); a1=fmaf(w2,q,a1);
        UNPK(v2.y,p,q); a2=fmaf(w2,p,a2); a3=fmaf(w2,q,a3);
        UNPK(v2.z,p,q); a4=fmaf(w2,p,a4); a5=fmaf(w2,q,a5);
        UNPK(v2.w,p,q); a6=fmaf(w2,p,a6); a7=fmaf(w2,q,a7);
        UNPK(v3.x,p,q); a0=fmaf(w3,p,a0); a1=fmaf(w3,q,a1);
        UNPK(v3.y,p,q); a2=fmaf(w3,p,a2); a3=fmaf(w3,q,a3);
        UNPK(v3.z,p,q); a4=fmaf(w3,p,a4); a5=fmaf(w3,q,a5);
        UNPK(v3.w,p,q); a6=fmaf(w3,p,a6); a7=fmaf(w3,q,a7);
    }
    // combine the two halves (each lane pairs with lane^32 holding same dims)
    a0 += __shfl_xor(a0, 32, 64); a1 += __shfl_xor(a1, 32, 64);
    a2 += __shfl_xor(a2, 32, 64); a3 += __shfl_xor(a3, 32, 64);
    a4 += __shfl_xor(a4, 32, 64); a5 += __shfl_xor(a5, 32, 64);
    a6 += __shfl_xor(a6, 32, 64); a7 += __shfl_xor(a7, 32, 64);

    float4 b0 = *(const float4*)(bias + d8);
    float4 b1 = *(const float4*)(bias + d8 + 4);
    a0 += b0.x; a1 += b0.y; a2 += b0.z; a3 += b0.w;
    a4 += b1.x; a5 += b1.y; a6 += b1.z; a7 += b1.w;
    float s1 = a0+a1+a2+a3+a4+a5+a6+a7;
    float s2 = a0*a0+a1*a1+a2*a2+a3*a3+a4*a4+a5*a5+a6*a6+a7*a7;
    for (int o = 16; o >= 1; o >>= 1) {
        s1 += __shfl_xor(s1, o, 64);
        s2 += __shfl_xor(s2, o, 64);
    }
    float mean = s1 * (1.0f / 256.0f);
    float var = s2 * (1.0f / 256.0f) - mean * mean;
    float rstd = rsqrtf(var + 1e-5f);
    if (half == 0) {
        float4 g0 = *(const float4*)(gamma + d8);
        float4 g1 = *(const float4*)(gamma + d8 + 4);
        float4 e0 = *(const float4*)(beta + d8);
        float4 e1 = *(const float4*)(beta + d8 + 4);
        float y0 = fmaxf((a0 - mean) * rstd * g0.x + e0.x, 0.0f);
        float y1 = fmaxf((a1 - mean) * rstd * g0.y + e0.y, 0.0f);
        float y2 = fmaxf((a2 - mean) * rstd * g0.z + e0.z, 0.0f);
        float y3 = fmaxf((a3 - mean) * rstd * g0.w + e0.w, 0.0f);
        float y4 = fmaxf((a4 - mean) * rstd * g1.x + e1.x, 0.0f);
        float y5 = fmaxf((a5 - mean) * rstd * g1.y + e1.y, 0.0f);
        float y6 = fmaxf((a6 - mean) * rstd * g1.z + e1.z, 0.0f);
        float y7 = fmaxf((a7 - mean) * rstd * g1.w + e1.w, 0.0f);
        uint4 o;
        o.x = pack2(y0, y1);
        o.y = pack2(y2, y3);
        o.z = pack2(y4, y5);
        o.w = pack2(y6, y7);
        *(uint4*)(xo + node * 256 + d8) = o;
    }
}

__global__ __launch_bounds__(256) void k_gather(const u16* __restrict__ x,
                                                const int* __restrict__ tgt,
                                                u16* __restrict__ xt) {
    int wave = threadIdx.x >> 6, lane = threadIdx.x & 63;
    int row = blockIdx.x * 4 + wave;
    int t = tgt[row];
    *(ushort4*)(xt + row * 256 + lane * 4) =
        *(const ushort4*)(x + t * 256 + lane * 4);
}

__global__ __launch_bounds__(256) void k_lnrelu(const u16* __restrict__ h,
                                                const float* __restrict__ bias,
                                                const float* __restrict__ gamma,
                                                const float* __restrict__ beta,
                                                u16* __restrict__ xo) {
    int wave = threadIdx.x >> 6, lane = threadIdx.x & 63;
    int row = blockIdx.x * 4 + wave;
    int base = row * 256 + lane * 4;
    ushort4 hv = *(const ushort4*)(h + base);
    float4 bv = *(const float4*)(bias + lane * 4);
    float a0 = bf2f(hv.x) + bv.x, a1 = bf2f(hv.y) + bv.y;
    float a2 = bf2f(hv.z) + bv.z, a3 = bf2f(hv.w) + bv.w;
    float s1 = a0 + a1 + a2 + a3;
    float s2 = a0 * a0 + a1 * a1 + a2 * a2 + a3 * a3;
    for (int o = 32; o >= 1; o >>= 1) {
        s1 += __shfl_xor(s1, o, 64);
        s2 += __shfl_xor(s2, o, 64);
    }
    float mean = s1 * (1.0f / 256.0f);
    float var = s2 * (1.0f / 256.0f) - mean * mean;
    float rstd = rsqrtf(var + 1e-5f);
    float4 gv = *(const float4*)(gamma + lane * 4);
    float4 be = *(const float4*)(beta + lane * 4);
    float y0 = fmaxf((a0 - mean) * rstd * gv.x + be.x, 0.0f);
    float y1 = fmaxf((a1 - mean) * rstd * gv.y + be.y, 0.0f);
    float y2 = fmaxf((a2 - mean) * rstd * gv.z + be.z, 0.0f);
    float y3 = fmaxf((a3 - mean) * rstd * gv.w + be.w, 0.0f);
    ushort4 o4;
    o4.x = f2bf(y0); o4.y = f2bf(y1); o4.z = f2bf(y2); o4.w = f2bf(y3);
    *(ushort4*)(xo + base) = o4;
}

__global__ __launch_bounds__(256) void k_out(const u16* __restrict__ x,
                                             const float* __restrict__ W,
                                             const float* __restrict__ b,
                                             float* __restrict__ out) {
    int wave = threadIdx.x >> 6, lane = threadIdx.x & 63;
    int row = blockIdx.x * 4 + wave;
    ushort4 v = *(const ushort4*)(x + row * 256 + lane * 4);
    float x0 = bf2f(v.x), x1 = bf2f(v.y), x2 = bf2f(v.z), x3 = bf2f(v.w);
    int d = lane * 4;
    for (int o = 0; o < NOUT; o++) {
        float p = x0 * W[(d + 0) * NOUT + o] + x1 * W[(d + 1) * NOUT + o] +
                  x2 * W[(d + 2) * NOUT + o] + x3 * W[(d + 3) * NOUT + o];
        for (int off = 32; off >= 1; off >>= 1) p += __shfl_xor(p, off, 64);
        if (lane == 0) out[row * NOUT + o] = p + b[o];
    }
}

extern "C" void kernel_launch(void* const* d_in, const int* in_sizes, int n_in,
                              void* d_out, int out_size, void* d_ws, size_t ws_size,
                              hipStream_t stream) {
    (void)in_sizes; (void)n_in; (void)out_size; (void)ws_size;
    const int* tokens = (const int*)d_in[0];
    const int* edges = (const int*)d_in[1];
    const int* tgt = (const int*)d_in[2];
    const float* emb = (const float*)d_in[3];
    const float* gnn_W = (const float*)d_in[4];
    const float* gnn_b = (const float*)d_in[5];
    const float* gnn_g = (const float*)d_in[6];
    const float* gnn_be = (const float*)d_in[7];
    const float* lin_W = (const float*)d_in[8];
    const float* lin_b = (const float*)d_in[9];
    const float* lin_g = (const float*)d_in[10];
    const float* lin_be = (const float*)d_in[11];
    const float* out_W = (const float*)d_in[12];
    const float* out_b = (const float*)d_in[13];
    float* out = (float*)d_out;

    char* ws = (char*)d_ws;
    u16* x = (u16*)ws;           ws += (size_t)NN * 256 * 2;
    u16* h = (u16*)ws;           ws += (size_t)NN * 256 * 2;
    int* csr_src = (int*)ws;     ws += (size_t)NE * 4;
    int* recs = (int*)ws;        ws += (size_t)NE * 4;
    float* dinv = (float*)ws;    ws += (size_t)NN * 4;
    int* csr_off = (int*)ws;     ws += (size_t)(NN + 4) * 4;
    int* bucketCnt = (int*)ws;   ws += 256 * 4;
    int* bucketOff = (int*)ws;   ws += 256 * 4;
    int* bucketCur = (int*)ws;   ws += 256 * 4;
    u16* Wt = (u16*)ws;          ws += (size_t)6 * 65536 * 2;
    u16* xt = (u16*)ws;          ws += (size_t)NT * 256 * 2;
    u16* ht = (u16*)ws;          ws += (size_t)NT * 256 * 2;

    const int* e_src = edges;
    const int* e_dst = edges + NE;

    k_wt<<<1536, 256, 0, stream>>>(gnn_W, lin_W, Wt);
    k_embed<<<25000, 256, 0, stream>>>(tokens, emb, x);
    k_zero<<<1, 256, 0, stream>>>(bucketCnt, NBUCK);
    k_binA<<<782, 256, 0, stream>>>(e_dst, bucketCnt);
    k_bscan<<<1, 256, 0, stream>>>(bucketCnt, bucketOff, bucketCur);
    k_binB<<<782, 256, 0, stream>>>(e_src, e_dst, bucketCur, recs);
    k_csr<<<NBUCK, 256, 0, stream>>>(recs, bucketOff, csr_src, csr_off, dinv);

    for (int l = 0; l < 4; l++) {
        k_gemm<<<dim3(782, 2), 256, 0, stream>>>(x, Wt + l * 65536, h, NN);
        k_aggr<<<25000, 256, 0, stream>>>(h, csr_off, csr_src, dinv,
                                          gnn_b + l * 256, gnn_g + l * 256,
                                          gnn_be + l * 256, x);
    }
    k_gather<<<2048, 256, 0, stream>>>(x, tgt, xt);
    for (int l = 0; l < 2; l++) {
        k_gemm<<<dim3(64, 2), 256, 0, stream>>>(xt, Wt + (4 + l) * 65536, ht, NT);
        k_lnrelu<<<2048, 256, 0, stream>>>(ht, lin_b + l * 256, lin_g + l * 256,
                                           lin_be + l * 256, xt);
    }
    k_out<<<2048, 256, 0, stream>>>(xt, out_W, out_b, out);
}

// Round 6
// 1422.731 us; speedup vs baseline: 1.2203x; 1.0153x over previous
//
#include <hip/hip_runtime.h>

#define NN 100000
#define NE 3200000
#define DD 256
#define NT 8192
#define NOUT 10
#define NBUCK 196        // ceil(100000/512) buckets of 512 dst nodes
#define CSRP_CAP (NE + NBUCK * 4096 + 64)

typedef unsigned short u16;
typedef __attribute__((ext_vector_type(8))) short bf16x8;
typedef __attribute__((ext_vector_type(4))) float f32x4;

__device__ __forceinline__ float bf2f(u16 u) {
    union { unsigned int i; float f; } v; v.i = ((unsigned int)u) << 16; return v.f;
}
__device__ __forceinline__ u16 f2bf(float f) {
    union { float f; unsigned int i; } v; v.f = f;
    unsigned int x = v.i;
    return (u16)((x + 0x7fffu + ((x >> 16) & 1u)) >> 16);
}
__device__ __forceinline__ unsigned int pack2(float a, float b) {
    return (unsigned int)f2bf(a) | ((unsigned int)f2bf(b) << 16);
}

#define UNPK(u, lo, hi) { union{unsigned int i; float f;} _x,_y; \
    _x.i=(u)<<16; _y.i=(u)&0xffff0000u; lo=_x.f; hi=_y.f; }

// ---- weight convert + transpose: Wt[l][n][k] = bf16(W[l][k][n]) ----
__global__ __launch_bounds__(256) void k_wt(const float* __restrict__ gW,
                                            const float* __restrict__ lW,
                                            u16* __restrict__ Wt) {
    int idx = blockIdx.x * 256 + threadIdx.x;      // < 6*65536
    int l = idx >> 16;
    int nk = idx & 65535;
    int n = nk >> 8, k = nk & 255;
    float v = (l < 4) ? gW[l * 65536 + k * 256 + n]
                      : lW[(l - 4) * 65536 + k * 256 + n];
    Wt[idx] = f2bf(v);
}

// ---- embedding gather -> bf16 x : one wave per node, float4 loads ----
__global__ __launch_bounds__(256) void k_embed(const int* __restrict__ tokens,
                                               const float* __restrict__ emb,
                                               u16* __restrict__ x) {
    int wave = threadIdx.x >> 6, lane = threadIdx.x & 63;
    int n = blockIdx.x * 4 + wave;
    int t = tokens[n];
    float4 v = *(const float4*)(emb + t * 256 + lane * 4);
    ushort4 o;
    o.x = f2bf(v.x); o.y = f2bf(v.y); o.z = f2bf(v.z); o.w = f2bf(v.w);
    *(ushort4*)(x + n * 256 + lane * 4) = o;
}

__global__ __launch_bounds__(256) void k_zero(int* __restrict__ p, int n) {
    int i = blockIdx.x * 256 + threadIdx.x;
    if (i < n) p[i] = 0;
}

// ---- pass A: per-bucket edge counts ----
__global__ __launch_bounds__(256) void k_binA(const int* __restrict__ dst,
                                              int* __restrict__ bucketCnt) {
    __shared__ int hist[NBUCK];
    int t = threadIdx.x;
    if (t < NBUCK) hist[t] = 0;
    __syncthreads();
    int base = blockIdx.x * 4096;
#pragma unroll
    for (int i = 0; i < 16; i++) {
        int e = base + i * 256 + t;
        if (e < NE) atomicAdd(&hist[dst[e] >> 9], 1);
    }
    __syncthreads();
    if (t < NBUCK && hist[t] > 0) atomicAdd(&bucketCnt[t], hist[t]);
}

// ---- scan bucket counts -> bucketOff (stable) + bucketCur (cursor) ----
__global__ __launch_bounds__(256) void k_bscan(const int* __restrict__ bucketCnt,
                                               int* __restrict__ bucketOff,
                                               int* __restrict__ bucketCur) {
    __shared__ int s[256];
    int t = threadIdx.x;
    int v = (t < NBUCK) ? bucketCnt[t] : 0;
    s[t] = v;
    __syncthreads();
    for (int o = 1; o < 256; o <<= 1) {
        int a = (t >= o) ? s[t - o] : 0;
        __syncthreads();
        s[t] += a;
        __syncthreads();
    }
    if (t < NBUCK) {
        int ex = s[t] - v;
        bucketOff[t] = ex;
        bucketCur[t] = ex;
    }
    if (t == 0) bucketOff[NBUCK] = NE;
}

// ---- pass B: write records at ABSOLUTE bucket offsets ----
// record = (src << 9) | (dst & 511)   (src < 2^17)
__global__ __launch_bounds__(256) void k_binB(const int* __restrict__ src,
                                              const int* __restrict__ dst,
                                              int* __restrict__ bucketCur,
                                              int* __restrict__ recs) {
    __shared__ int hist[NBUCK];
    __shared__ int gbase[NBUCK];
    int t = threadIdx.x;
    if (t < NBUCK) hist[t] = 0;
    __syncthreads();
    int base = blockIdx.x * 4096;
    int recv[16], bks[16], rnk[16];
#pragma unroll
    for (int i = 0; i < 16; i++) {
        int e = base + i * 256 + t;
        int bk = -1, rec = 0;
        if (e < NE) {
            int s_ = src[e], d_ = dst[e];
            bk = d_ >> 9;
            rec = (s_ << 9) | (d_ & 511);
        }
        bks[i] = bk; recv[i] = rec;
    }
#pragma unroll
    for (int i = 0; i < 16; i++)
        rnk[i] = (bks[i] >= 0) ? atomicAdd(&hist[bks[i]], 1) : 0;
    __syncthreads();
    if (t < NBUCK) {
        int c = hist[t];
        gbase[t] = (c > 0) ? atomicAdd(&bucketCur[t], c) : 0;  // absolute
    }
    __syncthreads();
#pragma unroll
    for (int i = 0; i < 16; i++)
        if (bks[i] >= 0) {
            int pos = gbase[bks[i]] + rnk[i];
            pos = min(max(pos, 0), NE - 1);
            recs[pos] = recv[i];
        }
}

// ---- csrA: per-bucket count + padded scan -> nodeInfo/dinv/self/dummies ----
// csrp record = int2 {src, w_f32}; per node: [self][edges...][dummies] padded to 8
__global__ __launch_bounds__(256) void k_csrA(const int* __restrict__ recs,
                                              const int* __restrict__ bucketOff,
                                              int2* __restrict__ nodeInfo,
                                              float* __restrict__ dinv,
                                              int2* __restrict__ csrp) {
    __shared__ int cnt[512], off[512];
    int b = blockIdx.x, t = threadIdx.x;
    int beg = min(max(bucketOff[b], 0), NE);
    int end = min(max(bucketOff[b + 1], beg), NE);
    int n = end - beg;
    cnt[t] = 0; cnt[t + 256] = 0;
    __syncthreads();
    for (int i = t; i < n; i += 256)
        atomicAdd(&cnt[recs[beg + i] & 511], 1);
    __syncthreads();
    off[t] = (cnt[t] + 8) & ~7;            // padded size = cnt+1 self, rounded to 8
    off[t + 256] = (cnt[t + 256] + 8) & ~7;
    __syncthreads();
    for (int o = 1; o < 512; o <<= 1) {
        int v0 = (t >= o) ? off[t - o] : 0;
        int v1 = (t + 256 >= o) ? off[t + 256 - o] : 0;
        __syncthreads();
        off[t] += v0; off[t + 256] += v1;
        __syncthreads();
    }
    int base = beg + b * 4096;
    for (int k = t; k < 512; k += 256) {
        int node = b * 512 + k;
        if (node >= NN) continue;
        int pd = (cnt[k] + 8) & ~7;
        int nbeg = base + off[k] - pd;     // exclusive padded scan
        int2 ni; ni.x = nbeg; ni.y = pd;
        nodeInfo[node] = ni;
        float di = rsqrtf((float)(cnt[k] + 1));
        dinv[node] = di;
        float ws = di * di;
        int2 sr; sr.x = node; sr.y = __float_as_int(ws);
        csrp[nbeg] = sr;
        int2 z; z.x = 0; z.y = 0;
        for (int j = nbeg + 1 + cnt[k]; j < nbeg + pd; j++) csrp[j] = z;
    }
}

// ---- csrB: scatter edges with precomputed weight ----
__global__ __launch_bounds__(256) void k_csrB(const int* __restrict__ recs,
                                              const int* __restrict__ bucketOff,
                                              const int2* __restrict__ nodeInfo,
                                              const float* __restrict__ dinv,
                                              int2* __restrict__ csrp) {
    __shared__ int cur[512];
    int b = blockIdx.x, t = threadIdx.x;
    cur[t] = 0; cur[t + 256] = 0;
    __syncthreads();
    int beg = min(max(bucketOff[b], 0), NE);
    int end = min(max(bucketOff[b + 1], beg), NE);
    int n = end - beg;
    for (int i = t; i < n; i += 256) {
        int r = recs[beg + i];
        int dlow = r & 511;
        int s = min(max(r >> 9, 0), NN - 1);
        int node = b * 512 + dlow;
        int rk = atomicAdd(&cur[dlow], 1);
        int2 ni = nodeInfo[node];
        float w = dinv[s] * dinv[node];
        int pos = ni.x + 1 + rk;
        pos = min(max(pos, 0), CSRP_CAP - 1);
        int2 e2; e2.x = s; e2.y = __float_as_int(w);
        csrp[pos] = e2;
    }
}

// ---- bf16 MFMA GEMM: C[M,256] = A[M,256] @ Bt^T (Bt is [256 n][256 k]) ----
__global__ __launch_bounds__(256) void k_gemm(const u16* __restrict__ A,
                                              const u16* __restrict__ Bt,
                                              u16* __restrict__ C, int M) {
    __shared__ u16 As[128 * 32];
    __shared__ u16 Bs[128 * 32];
    const int tid = threadIdx.x;
    const int wave = tid >> 6, lane = tid & 63;
    const int wm = wave >> 1, wn = wave & 1;
    const int rowBase = blockIdx.x * 128;
    const int colBase = blockIdx.y * 128;
    const int quad = lane >> 4, l16 = lane & 15;

    f32x4 acc[4][4] = {};

    for (int k0 = 0; k0 < 256; k0 += 32) {
        for (int c = tid; c < 512; c += 256) {
            int r = c >> 2, kc = c & 3;
            int grow = rowBase + r;
            if (grow >= M) grow = M - 1;
            uint4 v = *(const uint4*)(A + grow * 256 + k0 + kc * 8);
            int p = kc ^ (r & 3);
            *(uint4*)(As + r * 32 + p * 8) = v;
        }
        for (int c = tid; c < 512; c += 256) {
            int r = c >> 2, kc = c & 3;
            uint4 v = *(const uint4*)(Bt + (colBase + r) * 256 + k0 + kc * 8);
            int p = kc ^ (r & 3);
            *(uint4*)(Bs + r * 32 + p * 8) = v;
        }
        __syncthreads();
        bf16x8 a_frag[4], b_frag[4];
        for (int i = 0; i < 4; i++) {
            int r = wm * 64 + i * 16 + l16;
            int p = quad ^ (r & 3);
            a_frag[i] = *(const bf16x8*)(As + r * 32 + p * 8);
        }
        for (int j = 0; j < 4; j++) {
            int r = wn * 64 + j * 16 + l16;
            int p = quad ^ (r & 3);
            b_frag[j] = *(const bf16x8*)(Bs + r * 32 + p * 8);
        }
        for (int i = 0; i < 4; i++)
            for (int j = 0; j < 4; j++)
                acc[i][j] = __builtin_amdgcn_mfma_f32_16x16x32_bf16(
                    a_frag[i], b_frag[j], acc[i][j], 0, 0, 0);
        __syncthreads();
    }
    for (int i = 0; i < 4; i++)
        for (int j = 0; j < 4; j++) {
            int col = colBase + wn * 64 + j * 16 + l16;
            for (int r = 0; r < 4; r++) {
                int row = rowBase + wm * 64 + i * 16 + quad * 4 + r;
                if (row < M) C[row * 256 + col] = f2bf(acc[i][j][r]);
            }
        }
}

// ---- fused aggregate + bias + LN + ReLU (padded CSR, precomputed w) ----
// One node per wave; two 32-lane halves each cover all 256 dims at 16 B/lane,
// half h processes records j+4h..j+4h+3 of each 8-record group.
__global__ __launch_bounds__(256) void k_aggr(const u16* __restrict__ h,
                                              const int2* __restrict__ nodeInfo,
                                              const int2* __restrict__ csrp,
                                              const float* __restrict__ bias,
                                              const float* __restrict__ gamma,
                                              const float* __restrict__ beta,
                                              u16* __restrict__ xo) {
    const int wave = threadIdx.x >> 6, lane = threadIdx.x & 63;
    const int half = lane >> 5, l32 = lane & 31;
    const int node = blockIdx.x * 4 + wave;
    const int d8 = l32 * 8;                  // 8 dims per lane
    int2 ni = nodeInfo[node];
    float a0=0,a1=0,a2=0,a3=0,a4=0,a5=0,a6=0,a7=0;
    const int2* cp = csrp + ni.x + half * 4;
    for (int j = 0; j < ni.y; j += 8, cp += 8) {
        int2 r0 = cp[0], r1 = cp[1], r2 = cp[2], r3 = cp[3];
        uint4 v0 = *(const uint4*)(h + r0.x * 256 + d8);
        uint4 v1 = *(const uint4*)(h + r1.x * 256 + d8);
        uint4 v2 = *(const uint4*)(h + r2.x * 256 + d8);
        uint4 v3 = *(const uint4*)(h + r3.x * 256 + d8);
        float w0 = __int_as_float(r0.y);
        float w1 = __int_as_float(r1.y);
        float w2 = __int_as_float(r2.y);
        float w3 = __int_as_float(r3.y);
        float p,q;
        UNPK(v0.x,p,q); a0=fmaf(w0,p,a0); a1=fmaf(w0,q,a1);
        UNPK(v0.y,p,q); a2=fmaf(w0,p,a2); a3=fmaf(w0,q,a3);
        UNPK(v0.z,p,q); a4=fmaf(w0,p,a4); a5=fmaf(w0,q,a5);
        UNPK(v0.w,p,q); a6=fmaf(w0,p,a6); a7=fmaf(w0,q,a7);
        UNPK(v1.x,p,q); a0=fmaf(w1,p,a0); a1=fmaf(w1,q,a1);
        UNPK(v1.y,p,q); a2=fmaf(w1,p,a2); a3=fmaf(w1,q,a3);
        UNPK(v1.z,p,q); a4=fmaf(w1,p,a4); a5=fmaf(w1,q,a5);
        UNPK(v1.w,p,q); a6=fmaf(w1,p,a6); a7=fmaf(w1,q,a7);
        UNPK(v2.x,p,q); a0=fmaf(w2,p,a0); a1=fmaf(w2,q,a1);
        UNPK(v2.y,p,q); a2=fmaf(w2,p,a2); a3=fmaf(w2,q,a3);
        UNPK(v2.z,p,q); a4=fmaf(w2,p,a4); a5=fmaf(w2,q,a5);
        UNPK(v2.w,p,q); a6=fmaf(w2,p,a6); a7=fmaf(w2,q,a7);
        UNPK(v3.x,p,q); a0=fmaf(w3,p,a0); a1=fmaf(w3,q,a1);
        UNPK(v3.y,p,q); a2=fmaf(w3,p,a2); a3=fmaf(w3,q,a3);
        UNPK(v3.z,p,q); a4=fmaf(w3,p,a4); a5=fmaf(w3,q,a5);
        UNPK(v3.w,p,q); a6=fmaf(w3,p,a6); a7=fmaf(w3,q,a7);
    }
    // combine the two halves (lane pairs with lane^32 holding same dims)
    a0 += __shfl_xor(a0, 32, 64); a1 += __shfl_xor(a1, 32, 64);
    a2 += __shfl_xor(a2, 32, 64); a3 += __shfl_xor(a3, 32, 64);
    a4 += __shfl_xor(a4, 32, 64); a5 += __shfl_xor(a5, 32, 64);
    a6 += __shfl_xor(a6, 32, 64); a7 += __shfl_xor(a7, 32, 64);

    float4 b0 = *(const float4*)(bias + d8);
    float4 b1 = *(const float4*)(bias + d8 + 4);
    a0 += b0.x; a1 += b0.y; a2 += b0.z; a3 += b0.w;
    a4 += b1.x; a5 += b1.y; a6 += b1.z; a7 += b1.w;
    float s1 = a0+a1+a2+a3+a4+a5+a6+a7;
    float s2 = a0*a0+a1*a1+a2*a2+a3*a3+a4*a4+a5*a5+a6*a6+a7*a7;
    for (int o = 16; o >= 1; o >>= 1) {
        s1 += __shfl_xor(s1, o, 64);
        s2 += __shfl_xor(s2, o, 64);
    }
    float mean = s1 * (1.0f / 256.0f);
    float var = s2 * (1.0f / 256.0f) - mean * mean;
    float rstd = rsqrtf(var + 1e-5f);
    if (half == 0) {
        float4 g0 = *(const float4*)(gamma + d8);
        float4 g1 = *(const float4*)(gamma + d8 + 4);
        float4 e0 = *(const float4*)(beta + d8);
        float4 e1 = *(const float4*)(beta + d8 + 4);
        float y0 = fmaxf((a0 - mean) * rstd * g0.x + e0.x, 0.0f);
        float y1 = fmaxf((a1 - mean) * rstd * g0.y + e0.y, 0.0f);
        float y2 = fmaxf((a2 - mean) * rstd * g0.z + e0.z, 0.0f);
        float y3 = fmaxf((a3 - mean) * rstd * g0.w + e0.w, 0.0f);
        float y4 = fmaxf((a4 - mean) * rstd * g1.x + e1.x, 0.0f);
        float y5 = fmaxf((a5 - mean) * rstd * g1.y + e1.y, 0.0f);
        float y6 = fmaxf((a6 - mean) * rstd * g1.z + e1.z, 0.0f);
        float y7 = fmaxf((a7 - mean) * rstd * g1.w + e1.w, 0.0f);
        uint4 o;
        o.x = pack2(y0, y1);
        o.y = pack2(y2, y3);
        o.z = pack2(y4, y5);
        o.w = pack2(y6, y7);
        *(uint4*)(xo + node * 256 + d8) = o;
    }
}

__global__ __launch_bounds__(256) void k_gather(const u16* __restrict__ x,
                                                const int* __restrict__ tgt,
                                                u16* __restrict__ xt) {
    int wave = threadIdx.x >> 6, lane = threadIdx.x & 63;
    int row = blockIdx.x * 4 + wave;
    int t = tgt[row];
    *(ushort4*)(xt + row * 256 + lane * 4) =
        *(const ushort4*)(x + t * 256 + lane * 4);
}

__global__ __launch_bounds__(256) void k_lnrelu(const u16* __restrict__ h,
                                                const float* __restrict__ bias,
                                                const float* __restrict__ gamma,
                                                const float* __restrict__ beta,
                                                u16* __restrict__ xo) {
    int wave = threadIdx.x >> 6, lane = threadIdx.x & 63;
    int row = blockIdx.x * 4 + wave;
    int base = row * 256 + lane * 4;
    ushort4 hv = *(const ushort4*)(h + base);
    float4 bv = *(const float4*)(bias + lane * 4);
    float a0 = bf2f(hv.x) + bv.x, a1 = bf2f(hv.y) + bv.y;
    float a2 = bf2f(hv.z) + bv.z, a3 = bf2f(hv.w) + bv.w;
    float s1 = a0 + a1 + a2 + a3;
    float s2 = a0 * a0 + a1 * a1 + a2 * a2 + a3 * a3;
    for (int o = 32; o >= 1; o >>= 1) {
        s1 += __shfl_xor(s1, o, 64);
        s2 += __shfl_xor(s2, o, 64);
    }
    float mean = s1 * (1.0f / 256.0f);
    float var = s2 * (1.0f / 256.0f) - mean * mean;
    float rstd = rsqrtf(var + 1e-5f);
    float4 gv = *(const float4*)(gamma + lane * 4);
    float4 be = *(const float4*)(beta + lane * 4);
    float y0 = fmaxf((a0 - mean) * rstd * gv.x + be.x, 0.0f);
    float y1 = fmaxf((a1 - mean) * rstd * gv.y + be.y, 0.0f);
    float y2 = fmaxf((a2 - mean) * rstd * gv.z + be.z, 0.0f);
    float y3 = fmaxf((a3 - mean) * rstd * gv.w + be.w, 0.0f);
    ushort4 o4;
    o4.x = f2bf(y0); o4.y = f2bf(y1); o4.z = f2bf(y2); o4.w = f2bf(y3);
    *(ushort4*)(xo + base) = o4;
}

__global__ __launch_bounds__(256) void k_out(const u16* __restrict__ x,
                                             const float* __restrict__ W,
                                             const float* __restrict__ b,
                                             float* __restrict__ out) {
    int wave = threadIdx.x >> 6, lane = threadIdx.x & 63;
    int row = blockIdx.x * 4 + wave;
    ushort4 v = *(const ushort4*)(x + row * 256 + lane * 4);
    float x0 = bf2f(v.x), x1 = bf2f(v.y), x2 = bf2f(v.z), x3 = bf2f(v.w);
    int d = lane * 4;
    for (int o = 0; o < NOUT; o++) {
        float p = x0 * W[(d + 0) * NOUT + o] + x1 * W[(d + 1) * NOUT + o] +
                  x2 * W[(d + 2) * NOUT + o] + x3 * W[(d + 3) * NOUT + o];
        for (int off = 32; off >= 1; off >>= 1) p += __shfl_xor(p, off, 64);
        if (lane == 0) out[row * NOUT + o] = p + b[o];
    }
}

extern "C" void kernel_launch(void* const* d_in, const int* in_sizes, int n_in,
                              void* d_out, int out_size, void* d_ws, size_t ws_size,
                              hipStream_t stream) {
    (void)in_sizes; (void)n_in; (void)out_size; (void)ws_size;
    const int* tokens = (const int*)d_in[0];
    const int* edges = (const int*)d_in[1];
    const int* tgt = (const int*)d_in[2];
    const float* emb = (const float*)d_in[3];
    const float* gnn_W = (const float*)d_in[4];
    const float* gnn_b = (const float*)d_in[5];
    const float* gnn_g = (const float*)d_in[6];
    const float* gnn_be = (const float*)d_in[7];
    const float* lin_W = (const float*)d_in[8];
    const float* lin_b = (const float*)d_in[9];
    const float* lin_g = (const float*)d_in[10];
    const float* lin_be = (const float*)d_in[11];
    const float* out_W = (const float*)d_in[12];
    const float* out_b = (const float*)d_in[13];
    float* out = (float*)d_out;

    char* ws = (char*)d_ws;
    u16* x = (u16*)ws;           ws += (size_t)NN * 256 * 2;
    // h aliases recs: recs dead before first k_gemm writes h
    char* hreg = ws;             ws += (size_t)NN * 256 * 2;
    u16* h = (u16*)hreg;
    int* recs = (int*)hreg;      // NE*4 = 12.8MB < 51.2MB
    int2* csrp = (int2*)ws;      ws += (size_t)CSRP_CAP * 8;
    int2* nodeInfo = (int2*)ws;  ws += (size_t)NN * 8;
    float* dinv = (float*)ws;    ws += (size_t)NN * 4;
    int* bucketCnt = (int*)ws;   ws += 256 * 4;
    int* bucketOff = (int*)ws;   ws += 256 * 4;
    int* bucketCur = (int*)ws;   ws += 256 * 4;
    u16* Wt = (u16*)ws;          ws += (size_t)6 * 65536 * 2;
    u16* xt = (u16*)ws;          ws += (size_t)NT * 256 * 2;
    u16* ht = (u16*)ws;          ws += (size_t)NT * 256 * 2;

    const int* e_src = edges;
    const int* e_dst = edges + NE;

    k_wt<<<1536, 256, 0, stream>>>(gnn_W, lin_W, Wt);
    k_embed<<<25000, 256, 0, stream>>>(tokens, emb, x);
    k_zero<<<1, 256, 0, stream>>>(bucketCnt, NBUCK);
    k_binA<<<782, 256, 0, stream>>>(e_dst, bucketCnt);
    k_bscan<<<1, 256, 0, stream>>>(bucketCnt, bucketOff, bucketCur);
    k_binB<<<782, 256, 0, stream>>>(e_src, e_dst, bucketCur, recs);
    k_csrA<<<NBUCK, 256, 0, stream>>>(recs, bucketOff, nodeInfo, dinv, csrp);
    k_csrB<<<NBUCK, 256, 0, stream>>>(recs, bucketOff, nodeInfo, dinv, csrp);

    for (int l = 0; l < 4; l++) {
        k_gemm<<<dim3(782, 2), 256, 0, stream>>>(x, Wt + l * 65536, h, NN);
        k_aggr<<<25000, 256, 0, stream>>>(h, nodeInfo, csrp,
                                          gnn_b + l * 256, gnn_g + l * 256,
                                          gnn_be + l * 256, x);
    }
    k_gather<<<2048, 256, 0, stream>>>(x, tgt, xt);
    for (int l = 0; l < 2; l++) {
        k_gemm<<<dim3(64, 2), 256, 0, stream>>>(xt, Wt + (4 + l) * 65536, ht, NT);
        k_lnrelu<<<2048, 256, 0, stream>>>(ht, lin_b + l * 256, lin_g + l * 256,
                                           lin_be + l * 256, xt);
    }
    k_out<<<2048, 256, 0, stream>>>(xt, out_W, out_b, out);
}

// Round 7
// 1367.432 us; speedup vs baseline: 1.2697x; 1.0404x over previous
//
#include <hip/hip_runtime.h>
#include <hip/hip_fp16.h>

#define NN 100000
#define NE 3200000
#define DD 256
#define NT 8192
#define NOUT 10
#define NBUCK 196        // ceil(100000/512) buckets of 512 dst nodes
// per bucket: edges + 512 self + <=512*7 pad + 8 align slack
#define CSRP_CAP (NE + NBUCK * 4112 + 64)

typedef unsigned short u16;
typedef unsigned int u32;
typedef __attribute__((ext_vector_type(8))) short bf16x8;
typedef __attribute__((ext_vector_type(4))) float f32x4;

__device__ __forceinline__ float bf2f(u16 u) {
    union { unsigned int i; float f; } v; v.i = ((unsigned int)u) << 16; return v.f;
}
__device__ __forceinline__ u16 f2bf(float f) {
    union { float f; unsigned int i; } v; v.f = f;
    unsigned int x = v.i;
    return (u16)((x + 0x7fffu + ((x >> 16) & 1u)) >> 16);
}
__device__ __forceinline__ unsigned int pack2(float a, float b) {
    return (unsigned int)f2bf(a) | ((unsigned int)f2bf(b) << 16);
}
// pack src(17b) | fp16-no-sign(15b); w>0 always
__device__ __forceinline__ u32 packrec(int src, float w) {
    unsigned short h = __half_as_ushort(__float2half(w));
    return ((u32)src << 15) | (u32)(h & 0x7fff);
}
__device__ __forceinline__ float recw(u32 r) {
    return __half2float(__ushort_as_half((unsigned short)(r & 0x7fff)));
}

#define UNPK(u, lo, hi) { union{unsigned int i; float f;} _x,_y; \
    _x.i=(u)<<16; _y.i=(u)&0xffff0000u; lo=_x.f; hi=_y.f; }

__device__ __forceinline__ void gl2lds16(const void* g, void* l) {
    __builtin_amdgcn_global_load_lds(
        (const __attribute__((address_space(1))) unsigned int*)g,
        (__attribute__((address_space(3))) unsigned int*)l, 16, 0, 0);
}

// ---- weight convert + transpose: Wt[l][n][k] = bf16(W[l][k][n]) ----
__global__ __launch_bounds__(256) void k_wt(const float* __restrict__ gW,
                                            const float* __restrict__ lW,
                                            u16* __restrict__ Wt) {
    int idx = blockIdx.x * 256 + threadIdx.x;      // < 6*65536
    int l = idx >> 16;
    int nk = idx & 65535;
    int n = nk >> 8, k = nk & 255;
    float v = (l < 4) ? gW[l * 65536 + k * 256 + n]
                      : lW[(l - 4) * 65536 + k * 256 + n];
    Wt[idx] = f2bf(v);
}

// ---- embedding gather -> bf16 x : one wave per node, float4 loads ----
__global__ __launch_bounds__(256) void k_embed(const int* __restrict__ tokens,
                                               const float* __restrict__ emb,
                                               u16* __restrict__ x) {
    int wave = threadIdx.x >> 6, lane = threadIdx.x & 63;
    int n = blockIdx.x * 4 + wave;
    int t = tokens[n];
    float4 v = *(const float4*)(emb + t * 256 + lane * 4);
    ushort4 o;
    o.x = f2bf(v.x); o.y = f2bf(v.y); o.z = f2bf(v.z); o.w = f2bf(v.w);
    *(ushort4*)(x + n * 256 + lane * 4) = o;
}

__global__ __launch_bounds__(256) void k_zero(int* __restrict__ p, int n) {
    int i = blockIdx.x * 256 + threadIdx.x;
    if (i < n) p[i] = 0;
}

// ---- pass A: per-bucket edge counts ----
__global__ __launch_bounds__(256) void k_binA(const int* __restrict__ dst,
                                              int* __restrict__ bucketCnt) {
    __shared__ int hist[NBUCK];
    int t = threadIdx.x;
    if (t < NBUCK) hist[t] = 0;
    __syncthreads();
    int base = blockIdx.x * 4096;
#pragma unroll
    for (int i = 0; i < 16; i++) {
        int e = base + i * 256 + t;
        if (e < NE) atomicAdd(&hist[dst[e] >> 9], 1);
    }
    __syncthreads();
    if (t < NBUCK && hist[t] > 0) atomicAdd(&bucketCnt[t], hist[t]);
}

// ---- scan bucket counts -> bucketOff (stable) + bucketCur (cursor) ----
__global__ __launch_bounds__(256) void k_bscan(const int* __restrict__ bucketCnt,
                                               int* __restrict__ bucketOff,
                                               int* __restrict__ bucketCur) {
    __shared__ int s[256];
    int t = threadIdx.x;
    int v = (t < NBUCK) ? bucketCnt[t] : 0;
    s[t] = v;
    __syncthreads();
    for (int o = 1; o < 256; o <<= 1) {
        int a = (t >= o) ? s[t - o] : 0;
        __syncthreads();
        s[t] += a;
        __syncthreads();
    }
    if (t < NBUCK) {
        int ex = s[t] - v;
        bucketOff[t] = ex;
        bucketCur[t] = ex;
    }
    if (t == 0) bucketOff[NBUCK] = NE;
}

// ---- pass B: write records at ABSOLUTE bucket offsets ----
// record = (src << 9) | (dst & 511)   (src < 2^17)
__global__ __launch_bounds__(256) void k_binB(const int* __restrict__ src,
                                              const int* __restrict__ dst,
                                              int* __restrict__ bucketCur,
                                              int* __restrict__ recs) {
    __shared__ int hist[NBUCK];
    __shared__ int gbase[NBUCK];
    int t = threadIdx.x;
    if (t < NBUCK) hist[t] = 0;
    __syncthreads();
    int base = blockIdx.x * 4096;
    int recv[16], bks[16], rnk[16];
#pragma unroll
    for (int i = 0; i < 16; i++) {
        int e = base + i * 256 + t;
        int bk = -1, rec = 0;
        if (e < NE) {
            int s_ = src[e], d_ = dst[e];
            bk = d_ >> 9;
            rec = (s_ << 9) | (d_ & 511);
        }
        bks[i] = bk; recv[i] = rec;
    }
#pragma unroll
    for (int i = 0; i < 16; i++)
        rnk[i] = (bks[i] >= 0) ? atomicAdd(&hist[bks[i]], 1) : 0;
    __syncthreads();
    if (t < NBUCK) {
        int c = hist[t];
        gbase[t] = (c > 0) ? atomicAdd(&bucketCur[t], c) : 0;  // absolute
    }
    __syncthreads();
#pragma unroll
    for (int i = 0; i < 16; i++)
        if (bks[i] >= 0) {
            int pos = gbase[bks[i]] + rnk[i];
            pos = min(max(pos, 0), NE - 1);
            recs[pos] = recv[i];
        }
}

// ---- csrA: per-bucket count + padded scan -> nodeInfo/dinv/self/dummies ----
// csrp record = u32 (src<<15)|fp16w; per node: [self][edges...][dummies] pad 8
__global__ __launch_bounds__(256) void k_csrA(const int* __restrict__ recs,
                                              const int* __restrict__ bucketOff,
                                              int2* __restrict__ nodeInfo,
                                              float* __restrict__ dinv,
                                              u32* __restrict__ csrp) {
    __shared__ int cnt[512], off[512];
    int b = blockIdx.x, t = threadIdx.x;
    int beg = min(max(bucketOff[b], 0), NE);
    int end = min(max(bucketOff[b + 1], beg), NE);
    int n = end - beg;
    cnt[t] = 0; cnt[t + 256] = 0;
    __syncthreads();
    for (int i = t; i < n; i += 256)
        atomicAdd(&cnt[recs[beg + i] & 511], 1);
    __syncthreads();
    off[t] = (cnt[t] + 8) & ~7;            // padded size: cnt+1 self, round to 8
    off[t + 256] = (cnt[t + 256] + 8) & ~7;
    __syncthreads();
    for (int o = 1; o < 512; o <<= 1) {
        int v0 = (t >= o) ? off[t - o] : 0;
        int v1 = (t + 256 >= o) ? off[t + 256 - o] : 0;
        __syncthreads();
        off[t] += v0; off[t + 256] += v1;
        __syncthreads();
    }
    int base = (beg + b * 4112 + 7) & ~7;  // 8-record aligned bucket region
    for (int k = t; k < 512; k += 256) {
        int node = b * 512 + k;
        if (node >= NN) continue;
        int pd = (cnt[k] + 8) & ~7;
        int nbeg = base + off[k] - pd;     // exclusive padded scan (8-aligned)
        int2 ni; ni.x = nbeg; ni.y = pd;
        nodeInfo[node] = ni;
        float di = rsqrtf((float)(cnt[k] + 1));
        dinv[node] = di;
        csrp[nbeg] = packrec(node, di * di);
        for (int j = nbeg + 1 + cnt[k]; j < nbeg + pd; j++) csrp[j] = 0u;
    }
}

// ---- csrB: scatter edges with precomputed fp16 weight ----
__global__ __launch_bounds__(256) void k_csrB(const int* __restrict__ recs,
                                              const int* __restrict__ bucketOff,
                                              const int2* __restrict__ nodeInfo,
                                              const float* __restrict__ dinv,
                                              u32* __restrict__ csrp) {
    __shared__ int cur[512];
    int b = blockIdx.x, t = threadIdx.x;
    cur[t] = 0; cur[t + 256] = 0;
    __syncthreads();
    int beg = min(max(bucketOff[b], 0), NE);
    int end = min(max(bucketOff[b + 1], beg), NE);
    int n = end - beg;
    for (int i = t; i < n; i += 256) {
        int r = recs[beg + i];
        int dlow = r & 511;
        int s = min(max(r >> 9, 0), NN - 1);
        int node = b * 512 + dlow;
        int rk = atomicAdd(&cur[dlow], 1);
        int2 ni = nodeInfo[node];
        float w = dinv[s] * dinv[node];
        int pos = ni.x + 1 + rk;
        pos = min(max(pos, 0), CSRP_CAP - 1);
        csrp[pos] = packrec(s, w);
    }
}

// ---- bf16 MFMA GEMM, BK=64 double-buffered, global_load_lds staging ----
// C[M,256] = A[M,256] @ Bt^T   (Bt is [256 n][256 k])
__global__ __launch_bounds__(256) void k_gemm(const u16* __restrict__ A,
                                              const u16* __restrict__ Bt,
                                              u16* __restrict__ C, int M) {
    __shared__ __align__(16) u16 As[2][128 * 64];
    __shared__ __align__(16) u16 Bs[2][128 * 64];
    const int tid = threadIdx.x;
    const int wave = tid >> 6, lane = tid & 63;
    const int wm = wave >> 1, wn = wave & 1;
    const int rowBase = blockIdx.x * 128;
    const int colBase = blockIdx.y * 128;
    const int quad = lane >> 4, l16 = lane & 15;

    f32x4 acc[4][4] = {};

    // stage buffer buf with K window [k0, k0+64): 4 rounds x (4 waves x 64 lanes x 16B)
    // LDS layout [r][chunk] row-major, 8 chunks of 8 bf16; SOURCE chunk swizzled
    // by r&7 so ds_read_b128 frag reads land 2-way (free) on banks.
#define STAGE(buf, k0)                                                        \
    {                                                                         \
        _Pragma("unroll")                                                     \
        for (int i = 0; i < 4; i++) {                                         \
            int j = (i * 4 + wave) * 64 + lane;                               \
            int r = j >> 3, c = j & 7;                                        \
            int cg = c ^ (r & 7);                                             \
            int ga = rowBase + r; if (ga >= M) ga = M - 1;                    \
            gl2lds16(A + (size_t)ga * 256 + (k0) + cg * 8,                    \
                     &As[buf][(i * 4 + wave) * 512]);                         \
            gl2lds16(Bt + (size_t)(colBase + r) * 256 + (k0) + cg * 8,        \
                     &Bs[buf][(i * 4 + wave) * 512]);                         \
        }                                                                     \
    }

    STAGE(0, 0)
    __syncthreads();
    for (int kk = 0; kk < 4; kk++) {
        int buf = kk & 1;
        if (kk < 3) STAGE(buf ^ 1, (kk + 1) * 64)
        for (int ks = 0; ks < 2; ks++) {
            bf16x8 a_frag[4], b_frag[4];
            for (int i = 0; i < 4; i++) {
                int r = wm * 64 + i * 16 + l16;
                int ch = (ks * 4 + quad) ^ (r & 7);
                a_frag[i] = *(const bf16x8*)(&As[buf][r * 64 + ch * 8]);
            }
            for (int j = 0; j < 4; j++) {
                int r = wn * 64 + j * 16 + l16;
                int ch = (ks * 4 + quad) ^ (r & 7);
                b_frag[j] = *(const bf16x8*)(&Bs[buf][r * 64 + ch * 8]);
            }
            for (int i = 0; i < 4; i++)
                for (int j = 0; j < 4; j++)
                    acc[i][j] = __builtin_amdgcn_mfma_f32_16x16x32_bf16(
                        a_frag[i], b_frag[j], acc[i][j], 0, 0, 0);
        }
        if (kk < 3) __syncthreads();
    }
#undef STAGE
    for (int i = 0; i < 4; i++)
        for (int j = 0; j < 4; j++) {
            int col = colBase + wn * 64 + j * 16 + l16;
            for (int r = 0; r < 4; r++) {
                int row = rowBase + wm * 64 + i * 16 + quad * 4 + r;
                if (row < M) C[row * 256 + col] = f2bf(acc[i][j][r]);
            }
        }
}

// ---- fused aggregate + bias + LN + ReLU (padded CSR, packed u32 recs) ----
__global__ __launch_bounds__(256) void k_aggr(const u16* __restrict__ h,
                                              const int2* __restrict__ nodeInfo,
                                              const u32* __restrict__ csrp,
                                              const float* __restrict__ bias,
                                              const float* __restrict__ gamma,
                                              const float* __restrict__ beta,
                                              u16* __restrict__ xo) {
    const int wave = threadIdx.x >> 6, lane = threadIdx.x & 63;
    const int half = lane >> 5, l32 = lane & 31;
    const int node = blockIdx.x * 4 + wave;
    const int d8 = l32 * 8;                  // 8 dims per lane
    int2 ni = nodeInfo[node];
    float a0=0,a1=0,a2=0,a3=0,a4=0,a5=0,a6=0,a7=0;
    const u32* cp = csrp + ni.x + half * 4;
    for (int j = 0; j < ni.y; j += 8, cp += 8) {
        uint4 rr = *(const uint4*)cp;        // 4 packed records
        int s0 = rr.x >> 15, s1 = rr.y >> 15, s2 = rr.z >> 15, s3 = rr.w >> 15;
        uint4 v0 = *(const uint4*)(h + s0 * 256 + d8);
        uint4 v1 = *(const uint4*)(h + s1 * 256 + d8);
        uint4 v2 = *(const uint4*)(h + s2 * 256 + d8);
        uint4 v3 = *(const uint4*)(h + s3 * 256 + d8);
        float w0 = recw(rr.x), w1 = recw(rr.y), w2 = recw(rr.z), w3 = recw(rr.w);
        float p,q;
        UNPK(v0.x,p,q); a0=fmaf(w0,p,a0); a1=fmaf(w0,q,a1);
        UNPK(v0.y,p,q); a2=fmaf(w0,p,a2); a3=fmaf(w0,q,a3);
        UNPK(v0.z,p,q); a4=fmaf(w0,p,a4); a5=fmaf(w0,q,a5);
        UNPK(v0.w,p,q); a6=fmaf(w0,p,a6); a7=fmaf(w0,q,a7);
        UNPK(v1.x,p,q); a0=fmaf(w1,p,a0); a1=fmaf(w1,q,a1);
        UNPK(v1.y,p,q); a2=fmaf(w1,p,a2); a3=fmaf(w1,q,a3);
        UNPK(v1.z,p,q); a4=fmaf(w1,p,a4); a5=fmaf(w1,q,a5);
        UNPK(v1.w,p,q); a6=fmaf(w1,p,a6); a7=fmaf(w1,q,a7);
        UNPK(v2.x,p,q); a0=fmaf(w2,p,a0); a1=fmaf(w2,q,a1);
        UNPK(v2.y,p,q); a2=fmaf(w2,p,a2); a3=fmaf(w2,q,a3);
        UNPK(v2.z,p,q); a4=fmaf(w2,p,a4); a5=fmaf(w2,q,a5);
        UNPK(v2.w,p,q); a6=fmaf(w2,p,a6); a7=fmaf(w2,q,a7);
        UNPK(v3.x,p,q); a0=fmaf(w3,p,a0); a1=fmaf(w3,q,a1);
        UNPK(v3.y,p,q); a2=fmaf(w3,p,a2); a3=fmaf(w3,q,a3);
        UNPK(v3.z,p,q); a4=fmaf(w3,p,a4); a5=fmaf(w3,q,a5);
        UNPK(v3.w,p,q); a6=fmaf(w3,p,a6); a7=fmaf(w3,q,a7);
    }
    a0 += __shfl_xor(a0, 32, 64); a1 += __shfl_xor(a1, 32, 64);
    a2 += __shfl_xor(a2, 32, 64); a3 += __shfl_xor(a3, 32, 64);
    a4 += __shfl_xor(a4, 32, 64); a5 += __shfl_xor(a5, 32, 64);
    a6 += __shfl_xor(a6, 32, 64); a7 += __shfl_xor(a7, 32, 64);

    float4 b0 = *(const float4*)(bias + d8);
    float4 b1 = *(const float4*)(bias + d8 + 4);
    a0 += b0.x; a1 += b0.y; a2 += b0.z; a3 += b0.w;
    a4 += b1.x; a5 += b1.y; a6 += b1.z; a7 += b1.w;
    float s1 = a0+a1+a2+a3+a4+a5+a6+a7;
    float s2 = a0*a0+a1*a1+a2*a2+a3*a3+a4*a4+a5*a5+a6*a6+a7*a7;
    for (int o = 16; o >= 1; o >>= 1) {
        s1 += __shfl_xor(s1, o, 64);
        s2 += __shfl_xor(s2, o, 64);
    }
    float mean = s1 * (1.0f / 256.0f);
    float var = s2 * (1.0f / 256.0f) - mean * mean;
    float rstd = rsqrtf(var + 1e-5f);
    if (half == 0) {
        float4 g0 = *(const float4*)(gamma + d8);
        float4 g1 = *(const float4*)(gamma + d8 + 4);
        float4 e0 = *(const float4*)(beta + d8);
        float4 e1 = *(const float4*)(beta + d8 + 4);
        float y0 = fmaxf((a0 - mean) * rstd * g0.x + e0.x, 0.0f);
        float y1 = fmaxf((a1 - mean) * rstd * g0.y + e0.y, 0.0f);
        float y2 = fmaxf((a2 - mean) * rstd * g0.z + e0.z, 0.0f);
        float y3 = fmaxf((a3 - mean) * rstd * g0.w + e0.w, 0.0f);
        float y4 = fmaxf((a4 - mean) * rstd * g1.x + e1.x, 0.0f);
        float y5 = fmaxf((a5 - mean) * rstd * g1.y + e1.y, 0.0f);
        float y6 = fmaxf((a6 - mean) * rstd * g1.z + e1.z, 0.0f);
        float y7 = fmaxf((a7 - mean) * rstd * g1.w + e1.w, 0.0f);
        uint4 o;
        o.x = pack2(y0, y1);
        o.y = pack2(y2, y3);
        o.z = pack2(y4, y5);
        o.w = pack2(y6, y7);
        *(uint4*)(xo + node * 256 + d8) = o;
    }
}

__global__ __launch_bounds__(256) void k_gather(const u16* __restrict__ x,
                                                const int* __restrict__ tgt,
                                                u16* __restrict__ xt) {
    int wave = threadIdx.x >> 6, lane = threadIdx.x & 63;
    int row = blockIdx.x * 4 + wave;
    int t = tgt[row];
    *(ushort4*)(xt + row * 256 + lane * 4) =
        *(const ushort4*)(x + t * 256 + lane * 4);
}

__global__ __launch_bounds__(256) void k_lnrelu(const u16* __restrict__ h,
                                                const float* __restrict__ bias,
                                                const float* __restrict__ gamma,
                                                const float* __restrict__ beta,
                                                u16* __restrict__ xo) {
    int wave = threadIdx.x >> 6, lane = threadIdx.x & 63;
    int row = blockIdx.x * 4 + wave;
    int base = row * 256 + lane * 4;
    ushort4 hv = *(const ushort4*)(h + base);
    float4 bv = *(const float4*)(bias + lane * 4);
    float a0 = bf2f(hv.x) + bv.x, a1 = bf2f(hv.y) + bv.y;
    float a2 = bf2f(hv.z) + bv.z, a3 = bf2f(hv.w) + bv.w;
    float s1 = a0 + a1 + a2 + a3;
    float s2 = a0 * a0 + a1 * a1 + a2 * a2 + a3 * a3;
    for (int o = 32; o >= 1; o >>= 1) {
        s1 += __shfl_xor(s1, o, 64);
        s2 += __shfl_xor(s2, o, 64);
    }
    float mean = s1 * (1.0f / 256.0f);
    float var = s2 * (1.0f / 256.0f) - mean * mean;
    float rstd = rsqrtf(var + 1e-5f);
    float4 gv = *(const float4*)(gamma + lane * 4);
    float4 be = *(const float4*)(beta + lane * 4);
    float y0 = fmaxf((a0 - mean) * rstd * gv.x + be.x, 0.0f);
    float y1 = fmaxf((a1 - mean) * rstd * gv.y + be.y, 0.0f);
    float y2 = fmaxf((a2 - mean) * rstd * gv.z + be.z, 0.0f);
    float y3 = fmaxf((a3 - mean) * rstd * gv.w + be.w, 0.0f);
    ushort4 o4;
    o4.x = f2bf(y0); o4.y = f2bf(y1); o4.z = f2bf(y2); o4.w = f2bf(y3);
    *(ushort4*)(xo + base) = o4;
}

__global__ __launch_bounds__(256) void k_out(const u16* __restrict__ x,
                                             const float* __restrict__ W,
                                             const float* __restrict__ b,
                                             float* __restrict__ out) {
    int wave = threadIdx.x >> 6, lane = threadIdx.x & 63;
    int row = blockIdx.x * 4 + wave;
    ushort4 v = *(const ushort4*)(x + row * 256 + lane * 4);
    float x0 = bf2f(v.x), x1 = bf2f(v.y), x2 = bf2f(v.z), x3 = bf2f(v.w);
    int d = lane * 4;
    for (int o = 0; o < NOUT; o++) {
        float p = x0 * W[(d + 0) * NOUT + o] + x1 * W[(d + 1) * NOUT + o] +
                  x2 * W[(d + 2) * NOUT + o] + x3 * W[(d + 3) * NOUT + o];
        for (int off = 32; off >= 1; off >>= 1) p += __shfl_xor(p, off, 64);
        if (lane == 0) out[row * NOUT + o] = p + b[o];
    }
}

extern "C" void kernel_launch(void* const* d_in, const int* in_sizes, int n_in,
                              void* d_out, int out_size, void* d_ws, size_t ws_size,
                              hipStream_t stream) {
    (void)in_sizes; (void)n_in; (void)out_size; (void)ws_size;
    const int* tokens = (const int*)d_in[0];
    const int* edges = (const int*)d_in[1];
    const int* tgt = (const int*)d_in[2];
    const float* emb = (const float*)d_in[3];
    const float* gnn_W = (const float*)d_in[4];
    const float* gnn_b = (const float*)d_in[5];
    const float* gnn_g = (const float*)d_in[6];
    const float* gnn_be = (const float*)d_in[7];
    const float* lin_W = (const float*)d_in[8];
    const float* lin_b = (const float*)d_in[9];
    const float* lin_g = (const float*)d_in[10];
    const float* lin_be = (const float*)d_in[11];
    const float* out_W = (const float*)d_in[12];
    const float* out_b = (const float*)d_in[13];
    float* out = (float*)d_out;

    char* ws = (char*)d_ws;
    u16* x = (u16*)ws;           ws += (size_t)NN * 256 * 2;
    // h aliases recs: recs dead before first k_gemm writes h
    char* hreg = ws;             ws += (size_t)NN * 256 * 2;
    u16* h = (u16*)hreg;
    int* recs = (int*)hreg;      // NE*4 = 12.8MB < 51.2MB
    u32* csrp = (u32*)ws;        ws += (size_t)CSRP_CAP * 4;
    int2* nodeInfo = (int2*)ws;  ws += (size_t)NN * 8;
    float* dinv = (float*)ws;    ws += (size_t)NN * 4;
    int* bucketCnt = (int*)ws;   ws += 256 * 4;
    int* bucketOff = (int*)ws;   ws += 256 * 4;
    int* bucketCur = (int*)ws;   ws += 256 * 4;
    u16* Wt = (u16*)ws;          ws += (size_t)6 * 65536 * 2;
    u16* xt = (u16*)ws;          ws += (size_t)NT * 256 * 2;
    u16* ht = (u16*)ws;          ws += (size_t)NT * 256 * 2;

    const int* e_src = edges;
    const int* e_dst = edges + NE;

    k_wt<<<1536, 256, 0, stream>>>(gnn_W, lin_W, Wt);
    k_embed<<<25000, 256, 0, stream>>>(tokens, emb, x);
    k_zero<<<1, 256, 0, stream>>>(bucketCnt, NBUCK);
    k_binA<<<782, 256, 0, stream>>>(e_dst, bucketCnt);
    k_bscan<<<1, 256, 0, stream>>>(bucketCnt, bucketOff, bucketCur);
    k_binB<<<782, 256, 0, stream>>>(e_src, e_dst, bucketCur, recs);
    k_csrA<<<NBUCK, 256, 0, stream>>>(recs, bucketOff, nodeInfo, dinv, csrp);
    k_csrB<<<NBUCK, 256, 0, stream>>>(recs, bucketOff, nodeInfo, dinv, csrp);

    for (int l = 0; l < 4; l++) {
        k_gemm<<<dim3(782, 2), 256, 0, stream>>>(x, Wt + l * 65536, h, NN);
        k_aggr<<<25000, 256, 0, stream>>>(h, nodeInfo, csrp,
                                          gnn_b + l * 256, gnn_g + l * 256,
                                          gnn_be + l * 256, x);
    }
    k_gather<<<2048, 256, 0, stream>>>(x, tgt, xt);
    for (int l = 0; l < 2; l++) {
        k_gemm<<<dim3(64, 2), 256, 0, stream>>>(xt, Wt + (4 + l) * 65536, ht, NT);
        k_lnrelu<<<2048, 256, 0, stream>>>(ht, lin_b + l * 256, lin_g + l * 256,
                                           lin_be + l * 256, xt);
    }
    k_out<<<2048, 256, 0, stream>>>(xt, out_W, out_b, out);
}

// Round 10
// 1321.140 us; speedup vs baseline: 1.3141x; 1.0350x over previous
//
#include <hip/hip_runtime.h>
#include <hip/hip_fp16.h>

#define NN 100000
#define NE 3200000
#define DD 256
#define NT 8192
#define NOUT 10
#define NBUCK 196        // ceil(100000/512) buckets of 512 dst nodes
// per bucket: edges + 512 self + <=512*7 pad + 8 align slack
#define CSRP_CAP (NE + NBUCK * 4112 + 64)

typedef unsigned short u16;
typedef unsigned int u32;
typedef __attribute__((ext_vector_type(8))) short bf16x8;
typedef __attribute__((ext_vector_type(4))) float f32x4;

__device__ __forceinline__ float bf2f(u16 u) {
    union { unsigned int i; float f; } v; v.i = ((unsigned int)u) << 16; return v.f;
}
__device__ __forceinline__ u16 f2bf(float f) {
    union { float f; unsigned int i; } v; v.f = f;
    unsigned int x = v.i;
    return (u16)((x + 0x7fffu + ((x >> 16) & 1u)) >> 16);
}
__device__ __forceinline__ unsigned int pack2(float a, float b) {
    return (unsigned int)f2bf(a) | ((unsigned int)f2bf(b) << 16);
}
// pack src(17b) | fp16-no-sign(15b); w>0 always
__device__ __forceinline__ u32 packrec(int src, float w) {
    unsigned short h = __half_as_ushort(__float2half(w));
    return ((u32)src << 15) | (u32)(h & 0x7fff);
}
__device__ __forceinline__ float recw(u32 r) {
    return __half2float(__ushort_as_half((unsigned short)(r & 0x7fff)));
}

#define UNPK(u, lo, hi) { union{unsigned int i; float f;} _x,_y; \
    _x.i=(u)<<16; _y.i=(u)&0xffff0000u; lo=_x.f; hi=_y.f; }

__device__ __forceinline__ void gl2lds16(const void* g, void* l) {
    __builtin_amdgcn_global_load_lds(
        (const __attribute__((address_space(1))) unsigned int*)g,
        (__attribute__((address_space(3))) unsigned int*)l, 16, 0, 0);
}

// ---- weight convert + transpose: Wt[l][n][k] = bf16(W[l][k][n]) ----
__global__ __launch_bounds__(256) void k_wt(const float* __restrict__ gW,
                                            const float* __restrict__ lW,
                                            u16* __restrict__ Wt) {
    int idx = blockIdx.x * 256 + threadIdx.x;      // < 6*65536
    int l = idx >> 16;
    int nk = idx & 65535;
    int n = nk >> 8, k = nk & 255;
    float v = (l < 4) ? gW[l * 65536 + k * 256 + n]
                      : lW[(l - 4) * 65536 + k * 256 + n];
    Wt[idx] = f2bf(v);
}

__global__ __launch_bounds__(256) void k_zero(int* __restrict__ p, int n) {
    int i = blockIdx.x * 256 + threadIdx.x;
    if (i < n) p[i] = 0;
}

// ---- pass A: per-bucket edge counts ----
__global__ __launch_bounds__(256) void k_binA(const int* __restrict__ dst,
                                              int* __restrict__ bucketCnt) {
    __shared__ int hist[NBUCK];
    int t = threadIdx.x;
    if (t < NBUCK) hist[t] = 0;
    __syncthreads();
    int base = blockIdx.x * 4096;
#pragma unroll
    for (int i = 0; i < 16; i++) {
        int e = base + i * 256 + t;
        if (e < NE) atomicAdd(&hist[dst[e] >> 9], 1);
    }
    __syncthreads();
    if (t < NBUCK && hist[t] > 0) atomicAdd(&bucketCnt[t], hist[t]);
}

// ---- scan bucket counts -> bucketOff (stable) + bucketCur (cursor) ----
__global__ __launch_bounds__(256) void k_bscan(const int* __restrict__ bucketCnt,
                                               int* __restrict__ bucketOff,
                                               int* __restrict__ bucketCur) {
    __shared__ int s[256];
    int t = threadIdx.x;
    int v = (t < NBUCK) ? bucketCnt[t] : 0;
    s[t] = v;
    __syncthreads();
    for (int o = 1; o < 256; o <<= 1) {
        int a = (t >= o) ? s[t - o] : 0;
        __syncthreads();
        s[t] += a;
        __syncthreads();
    }
    if (t < NBUCK) {
        int ex = s[t] - v;
        bucketOff[t] = ex;
        bucketCur[t] = ex;
    }
    if (t == 0) bucketOff[NBUCK] = NE;
}

// ---- pass B: write records at ABSOLUTE bucket offsets ----
// record = (src << 9) | (dst & 511)   (src < 2^17)
__global__ __launch_bounds__(256) void k_binB(const int* __restrict__ src,
                                              const int* __restrict__ dst,
                                              int* __restrict__ bucketCur,
                                              int* __restrict__ recs) {
    __shared__ int hist[NBUCK];
    __shared__ int gbase[NBUCK];
    int t = threadIdx.x;
    if (t < NBUCK) hist[t] = 0;
    __syncthreads();
    int base = blockIdx.x * 4096;
    int recv[16], bks[16], rnk[16];
#pragma unroll
    for (int i = 0; i < 16; i++) {
        int e = base + i * 256 + t;
        int bk = -1, rec = 0;
        if (e < NE) {
            int s_ = src[e], d_ = dst[e];
            bk = d_ >> 9;
            rec = (s_ << 9) | (d_ & 511);
        }
        bks[i] = bk; recv[i] = rec;
    }
#pragma unroll
    for (int i = 0; i < 16; i++)
        rnk[i] = (bks[i] >= 0) ? atomicAdd(&hist[bks[i]], 1) : 0;
    __syncthreads();
    if (t < NBUCK) {
        int c = hist[t];
        gbase[t] = (c > 0) ? atomicAdd(&bucketCur[t], c) : 0;  // absolute
    }
    __syncthreads();
#pragma unroll
    for (int i = 0; i < 16; i++)
        if (bks[i] >= 0) {
            int pos = gbase[bks[i]] + rnk[i];
            pos = min(max(pos, 0), NE - 1);
            recs[pos] = recv[i];
        }
}

// ---- csrA: per-bucket count + padded scan -> nodeInfo/dinv/self/dummies ----
// csrp record = u32 (src<<15)|fp16w; per node: [self][edges...][dummies] pad 8
// NOTE: must be a SEPARATE dispatch from csrB — csrB reads dinv[s] for
// arbitrary s (cross-bucket); merging creates a cross-workgroup RAW race (R9).
__global__ __launch_bounds__(256) void k_csrA(const int* __restrict__ recs,
                                              const int* __restrict__ bucketOff,
                                              int2* __restrict__ nodeInfo,
                                              float* __restrict__ dinv,
                                              u32* __restrict__ csrp) {
    __shared__ int cnt[512], off[512];
    int b = blockIdx.x, t = threadIdx.x;
    int beg = min(max(bucketOff[b], 0), NE);
    int end = min(max(bucketOff[b + 1], beg), NE);
    int n = end - beg;
    cnt[t] = 0; cnt[t + 256] = 0;
    __syncthreads();
    for (int i = t; i < n; i += 256)
        atomicAdd(&cnt[recs[beg + i] & 511], 1);
    __syncthreads();
    off[t] = (cnt[t] + 8) & ~7;            // padded size: cnt+1 self, round to 8
    off[t + 256] = (cnt[t + 256] + 8) & ~7;
    __syncthreads();
    for (int o = 1; o < 512; o <<= 1) {
        int v0 = (t >= o) ? off[t - o] : 0;
        int v1 = (t + 256 >= o) ? off[t + 256 - o] : 0;
        __syncthreads();
        off[t] += v0; off[t + 256] += v1;
        __syncthreads();
    }
    int base = (beg + b * 4112 + 7) & ~7;  // 8-record aligned bucket region
    for (int k = t; k < 512; k += 256) {
        int node = b * 512 + k;
        if (node >= NN) continue;
        int pd = (cnt[k] + 8) & ~7;
        int nbeg = base + off[k] - pd;     // exclusive padded scan (8-aligned)
        int2 ni; ni.x = nbeg; ni.y = pd;
        nodeInfo[node] = ni;
        float di = rsqrtf((float)(cnt[k] + 1));
        dinv[node] = di;
        csrp[nbeg] = packrec(node, di * di);
        for (int j = nbeg + 1 + cnt[k]; j < nbeg + pd; j++) csrp[j] = 0u;
    }
}

// ---- csrB: scatter edges with precomputed fp16 weight ----
__global__ __launch_bounds__(256) void k_csrB(const int* __restrict__ recs,
                                              const int* __restrict__ bucketOff,
                                              const int2* __restrict__ nodeInfo,
                                              const float* __restrict__ dinv,
                                              u32* __restrict__ csrp) {
    __shared__ int cur[512];
    int b = blockIdx.x, t = threadIdx.x;
    cur[t] = 0; cur[t + 256] = 0;
    __syncthreads();
    int beg = min(max(bucketOff[b], 0), NE);
    int end = min(max(bucketOff[b + 1], beg), NE);
    int n = end - beg;
    for (int i = t; i < n; i += 256) {
        int r = recs[beg + i];
        int dlow = r & 511;
        int s = min(max(r >> 9, 0), NN - 1);
        int node = b * 512 + dlow;
        int rk = atomicAdd(&cur[dlow], 1);
        int2 ni = nodeInfo[node];
        float w = dinv[s] * dinv[node];
        int pos = ni.x + 1 + rk;
        pos = min(max(pos, 0), CSRP_CAP - 1);
        csrp[pos] = packrec(s, w);
    }
}

// ---- shared GEMM epilogue ----
#define GEMM_EPILOGUE                                                         \
    for (int i = 0; i < 4; i++)                                               \
        for (int j = 0; j < 4; j++) {                                         \
            int col = colBase + wn * 64 + j * 16 + l16;                       \
            for (int r = 0; r < 4; r++) {                                     \
                int row = rowBase + wm * 64 + i * 16 + quad * 4 + r;          \
                if (row < M) C[row * 256 + col] = f2bf(acc[i][j][r]);         \
            }                                                                 \
        }

#define GEMM_COMPUTE(ASRC, BSRC)                                              \
    for (int ks = 0; ks < 2; ks++) {                                          \
        bf16x8 a_frag[4], b_frag[4];                                          \
        for (int i = 0; i < 4; i++) {                                         \
            int r = wm * 64 + i * 16 + l16;                                   \
            int ch = (ks * 4 + quad) ^ (r & 7);                               \
            a_frag[i] = *(const bf16x8*)(&ASRC[r * 64 + ch * 8]);             \
        }                                                                     \
        for (int j = 0; j < 4; j++) {                                         \
            int r = wn * 64 + j * 16 + l16;                                   \
            int ch = (ks * 4 + quad) ^ (r & 7);                               \
            b_frag[j] = *(const bf16x8*)(&BSRC[r * 64 + ch * 8]);             \
        }                                                                     \
        for (int i = 0; i < 4; i++)                                           \
            for (int j = 0; j < 4; j++)                                       \
                acc[i][j] = __builtin_amdgcn_mfma_f32_16x16x32_bf16(          \
                    a_frag[i], b_frag[j], acc[i][j], 0, 0, 0);                \
    }

// ---- bf16 MFMA GEMM, BK=64 single-buffered, global_load_lds staging ----
// C[M,256] = A[M,256] @ Bt^T   (Bt is [256 n][256 k]); 32 KB LDS -> ~5 blk/CU
__global__ __launch_bounds__(256) void k_gemm(const u16* __restrict__ A,
                                              const u16* __restrict__ Bt,
                                              u16* __restrict__ C, int M) {
    __shared__ __align__(16) u16 As[128 * 64];
    __shared__ __align__(16) u16 Bs[128 * 64];
    const int tid = threadIdx.x;
    const int wave = tid >> 6, lane = tid & 63;
    const int wm = wave >> 1, wn = wave & 1;
    const int rowBase = blockIdx.x * 128;
    const int colBase = blockIdx.y * 128;
    const int quad = lane >> 4, l16 = lane & 15;

    f32x4 acc[4][4] = {};

    for (int kk = 0; kk < 4; kk++) {
        int k0 = kk * 64;
#pragma unroll
        for (int i = 0; i < 4; i++) {
            int j = (i * 4 + wave) * 64 + lane;    // task 0..1023
            int r = j >> 3, c = j & 7;
            int cg = c ^ (r & 7);                  // source-chunk swizzle
            int ga = rowBase + r; if (ga >= M) ga = M - 1;
            gl2lds16(A + (size_t)ga * 256 + k0 + cg * 8,
                     &As[(i * 4 + wave) * 512]);
            gl2lds16(Bt + (size_t)(colBase + r) * 256 + k0 + cg * 8,
                     &Bs[(i * 4 + wave) * 512]);
        }
        __syncthreads();
        GEMM_COMPUTE(As, Bs)
        __syncthreads();
    }
    GEMM_EPILOGUE
}

// ---- GEMM-1: A rows gathered from f32 embedding table (embed fused) ----
__global__ __launch_bounds__(256) void k_gemm_emb(const int* __restrict__ tokens,
                                                  const float* __restrict__ emb,
                                                  const u16* __restrict__ Bt,
                                                  u16* __restrict__ C, int M) {
    __shared__ __align__(16) u16 As[128 * 64];
    __shared__ __align__(16) u16 Bs[128 * 64];
    __shared__ int tokLDS[128];
    const int tid = threadIdx.x;
    const int wave = tid >> 6, lane = tid & 63;
    const int wm = wave >> 1, wn = wave & 1;
    const int rowBase = blockIdx.x * 128;
    const int colBase = blockIdx.y * 128;
    const int quad = lane >> 4, l16 = lane & 15;

    if (tid < 128) {
        int ga = rowBase + tid; if (ga >= M) ga = M - 1;
        tokLDS[tid] = tokens[ga];
    }
    f32x4 acc[4][4] = {};
    __syncthreads();

    for (int kk = 0; kk < 4; kk++) {
        int k0 = kk * 64;
#pragma unroll
        for (int i = 0; i < 4; i++) {
            int j = (i * 4 + wave) * 64 + lane;    // task 0..1023
            int r = j >> 3, c = j & 7;
            int cg = c ^ (r & 7);
            // A: gather f32 embedding row, convert to bf16, LDS write 16B
            const float* srcp = emb + (size_t)tokLDS[r] * 256 + k0 + cg * 8;
            float4 f0 = *(const float4*)srcp;
            float4 f1 = *(const float4*)(srcp + 4);
            uint4 pk;
            pk.x = pack2(f0.x, f0.y); pk.y = pack2(f0.z, f0.w);
            pk.z = pack2(f1.x, f1.y); pk.w = pack2(f1.z, f1.w);
            *(uint4*)(&As[j * 8]) = pk;
            // B: weights via global_load_lds
            gl2lds16(Bt + (size_t)(colBase + r) * 256 + k0 + cg * 8,
                     &Bs[(i * 4 + wave) * 512]);
        }
        __syncthreads();
        GEMM_COMPUTE(As, Bs)
        __syncthreads();
    }
    GEMM_EPILOGUE
}

// ---- fused aggregate + bias + LN + ReLU (padded CSR, packed u32 recs) ----
__global__ __launch_bounds__(256) void k_aggr(const u16* __restrict__ h,
                                              const int2* __restrict__ nodeInfo,
                                              const u32* __restrict__ csrp,
                                              const float* __restrict__ bias,
                                              const float* __restrict__ gamma,
                                              const float* __restrict__ beta,
                                              u16* __restrict__ xo) {
    const int wave = threadIdx.x >> 6, lane = threadIdx.x & 63;
    const int half = lane >> 5, l32 = lane & 31;
    const int node = blockIdx.x * 4 + wave;
    const int d8 = l32 * 8;                  // 8 dims per lane
    int2 ni = nodeInfo[node];
    float a0=0,a1=0,a2=0,a3=0,a4=0,a5=0,a6=0,a7=0;
    const u32* cp = csrp + ni.x + half * 4;
    for (int j = 0; j < ni.y; j += 8, cp += 8) {
        uint4 rr = *(const uint4*)cp;        // 4 packed records
        int s0 = rr.x >> 15, s1 = rr.y >> 15, s2 = rr.z >> 15, s3 = rr.w >> 15;
        uint4 v0 = *(const uint4*)(h + s0 * 256 + d8);
        uint4 v1 = *(const uint4*)(h + s1 * 256 + d8);
        uint4 v2 = *(const uint4*)(h + s2 * 256 + d8);
        uint4 v3 = *(const uint4*)(h + s3 * 256 + d8);
        float w0 = recw(rr.x), w1 = recw(rr.y), w2 = recw(rr.z), w3 = recw(rr.w);
        float p,q;
        UNPK(v0.x,p,q); a0=fmaf(w0,p,a0); a1=fmaf(w0,q,a1);
        UNPK(v0.y,p,q); a2=fmaf(w0,p,a2); a3=fmaf(w0,q,a3);
        UNPK(v0.z,p,q); a4=fmaf(w0,p,a4); a5=fmaf(w0,q,a5);
        UNPK(v0.w,p,q); a6=fmaf(w0,p,a6); a7=fmaf(w0,q,a7);
        UNPK(v1.x,p,q); a0=fmaf(w1,p,a0); a1=fmaf(w1,q,a1);
        UNPK(v1.y,p,q); a2=fmaf(w1,p,a2); a3=fmaf(w1,q,a3);
        UNPK(v1.z,p,q); a4=fmaf(w1,p,a4); a5=fmaf(w1,q,a5);
        UNPK(v1.w,p,q); a6=fmaf(w1,p,a6); a7=fmaf(w1,q,a7);
        UNPK(v2.x,p,q); a0=fmaf(w2,p,a0); a1=fmaf(w2,q,a1);
        UNPK(v2.y,p,q); a2=fmaf(w2,p,a2); a3=fmaf(w2,q,a3);
        UNPK(v2.z,p,q); a4=fmaf(w2,p,a4); a5=fmaf(w2,q,a5);
        UNPK(v2.w,p,q); a6=fmaf(w2,p,a6); a7=fmaf(w2,q,a7);
        UNPK(v3.x,p,q); a0=fmaf(w3,p,a0); a1=fmaf(w3,q,a1);
        UNPK(v3.y,p,q); a2=fmaf(w3,p,a2); a3=fmaf(w3,q,a3);
        UNPK(v3.z,p,q); a4=fmaf(w3,p,a4); a5=fmaf(w3,q,a5);
        UNPK(v3.w,p,q); a6=fmaf(w3,p,a6); a7=fmaf(w3,q,a7);
    }
    a0 += __shfl_xor(a0, 32, 64); a1 += __shfl_xor(a1, 32, 64);
    a2 += __shfl_xor(a2, 32, 64); a3 += __shfl_xor(a3, 32, 64);
    a4 += __shfl_xor(a4, 32, 64); a5 += __shfl_xor(a5, 32, 64);
    a6 += __shfl_xor(a6, 32, 64); a7 += __shfl_xor(a7, 32, 64);

    float4 b0 = *(const float4*)(bias + d8);
    float4 b1 = *(const float4*)(bias + d8 + 4);
    a0 += b0.x; a1 += b0.y; a2 += b0.z; a3 += b0.w;
    a4 += b1.x; a5 += b1.y; a6 += b1.z; a7 += b1.w;
    float s1 = a0+a1+a2+a3+a4+a5+a6+a7;
    float s2 = a0*a0+a1*a1+a2*a2+a3*a3+a4*a4+a5*a5+a6*a6+a7*a7;
    for (int o = 16; o >= 1; o >>= 1) {
        s1 += __shfl_xor(s1, o, 64);
        s2 += __shfl_xor(s2, o, 64);
    }
    float mean = s1 * (1.0f / 256.0f);
    float var = s2 * (1.0f / 256.0f) - mean * mean;
    float rstd = rsqrtf(var + 1e-5f);
    if (half == 0) {
        float4 g0 = *(const float4*)(gamma + d8);
        float4 g1 = *(const float4*)(gamma + d8 + 4);
        float4 e0 = *(const float4*)(beta + d8);
        float4 e1 = *(const float4*)(beta + d8 + 4);
        float y0 = fmaxf((a0 - mean) * rstd * g0.x + e0.x, 0.0f);
        float y1 = fmaxf((a1 - mean) * rstd * g0.y + e0.y, 0.0f);
        float y2 = fmaxf((a2 - mean) * rstd * g0.z + e0.z, 0.0f);
        float y3 = fmaxf((a3 - mean) * rstd * g0.w + e0.w, 0.0f);
        float y4 = fmaxf((a4 - mean) * rstd * g1.x + e1.x, 0.0f);
        float y5 = fmaxf((a5 - mean) * rstd * g1.y + e1.y, 0.0f);
        float y6 = fmaxf((a6 - mean) * rstd * g1.z + e1.z, 0.0f);
        float y7 = fmaxf((a7 - mean) * rstd * g1.w + e1.w, 0.0f);
        uint4 o;
        o.x = pack2(y0, y1);
        o.y = pack2(y2, y3);
        o.z = pack2(y4, y5);
        o.w = pack2(y6, y7);
        *(uint4*)(xo + node * 256 + d8) = o;
    }
}

__global__ __launch_bounds__(256) void k_gather(const u16* __restrict__ x,
                                                const int* __restrict__ tgt,
                                                u16* __restrict__ xt) {
    int wave = threadIdx.x >> 6, lane = threadIdx.x & 63;
    int row = blockIdx.x * 4 + wave;
    int t = tgt[row];
    *(ushort4*)(xt + row * 256 + lane * 4) =
        *(const ushort4*)(x + t * 256 + lane * 4);
}

__global__ __launch_bounds__(256) void k_lnrelu(const u16* __restrict__ h,
                                                const float* __restrict__ bias,
                                                const float* __restrict__ gamma,
                                                const float* __restrict__ beta,
                                                u16* __restrict__ xo) {
    int wave = threadIdx.x >> 6, lane = threadIdx.x & 63;
    int row = blockIdx.x * 4 + wave;
    int base = row * 256 + lane * 4;
    ushort4 hv = *(const ushort4*)(h + base);
    float4 bv = *(const float4*)(bias + lane * 4);
    float a0 = bf2f(hv.x) + bv.x, a1 = bf2f(hv.y) + bv.y;
    float a2 = bf2f(hv.z) + bv.z, a3 = bf2f(hv.w) + bv.w;
    float s1 = a0 + a1 + a2 + a3;
    float s2 = a0 * a0 + a1 * a1 + a2 * a2 + a3 * a3;
    for (int o = 32; o >= 1; o >>= 1) {
        s1 += __shfl_xor(s1, o, 64);
        s2 += __shfl_xor(s2, o, 64);
    }
    float mean = s1 * (1.0f / 256.0f);
    float var = s2 * (1.0f / 256.0f) - mean * mean;
    float rstd = rsqrtf(var + 1e-5f);
    float4 gv = *(const float4*)(gamma + lane * 4);
    float4 be = *(const float4*)(beta + lane * 4);
    float y0 = fmaxf((a0 - mean) * rstd * gv.x + be.x, 0.0f);
    float y1 = fmaxf((a1 - mean) * rstd * gv.y + be.y, 0.0f);
    float y2 = fmaxf((a2 - mean) * rstd * gv.z + be.z, 0.0f);
    float y3 = fmaxf((a3 - mean) * rstd * gv.w + be.w, 0.0f);
    ushort4 o4;
    o4.x = f2bf(y0); o4.y = f2bf(y1); o4.z = f2bf(y2); o4.w = f2bf(y3);
    *(ushort4*)(xo + base) = o4;
}

__global__ __launch_bounds__(256) void k_out(const u16* __restrict__ x,
                                             const float* __restrict__ W,
                                             const float* __restrict__ b,
                                             float* __restrict__ out) {
    int wave = threadIdx.x >> 6, lane = threadIdx.x & 63;
    int row = blockIdx.x * 4 + wave;
    ushort4 v = *(const ushort4*)(x + row * 256 + lane * 4);
    float x0 = bf2f(v.x), x1 = bf2f(v.y), x2 = bf2f(v.z), x3 = bf2f(v.w);
    int d = lane * 4;
    for (int o = 0; o < NOUT; o++) {
        float p = x0 * W[(d + 0) * NOUT + o] + x1 * W[(d + 1) * NOUT + o] +
                  x2 * W[(d + 2) * NOUT + o] + x3 * W[(d + 3) * NOUT + o];
        for (int off = 32; off >= 1; off >>= 1) p += __shfl_xor(p, off, 64);
        if (lane == 0) out[row * NOUT + o] = p + b[o];
    }
}

extern "C" void kernel_launch(void* const* d_in, const int* in_sizes, int n_in,
                              void* d_out, int out_size, void* d_ws, size_t ws_size,
                              hipStream_t stream) {
    (void)in_sizes; (void)n_in; (void)out_size; (void)ws_size;
    const int* tokens = (const int*)d_in[0];
    const int* edges = (const int*)d_in[1];
    const int* tgt = (const int*)d_in[2];
    const float* emb = (const float*)d_in[3];
    const float* gnn_W = (const float*)d_in[4];
    const float* gnn_b = (const float*)d_in[5];
    const float* gnn_g = (const float*)d_in[6];
    const float* gnn_be = (const float*)d_in[7];
    const float* lin_W = (const float*)d_in[8];
    const float* lin_b = (const float*)d_in[9];
    const float* lin_g = (const float*)d_in[10];
    const float* lin_be = (const float*)d_in[11];
    const float* out_W = (const float*)d_in[12];
    const float* out_b = (const float*)d_in[13];
    float* out = (float*)d_out;

    char* ws = (char*)d_ws;
    u16* x = (u16*)ws;           ws += (size_t)NN * 256 * 2;
    // h aliases recs: recs dead before first GEMM writes h
    char* hreg = ws;             ws += (size_t)NN * 256 * 2;
    u16* h = (u16*)hreg;
    int* recs = (int*)hreg;      // NE*4 = 12.8MB < 51.2MB
    u32* csrp = (u32*)ws;        ws += (size_t)CSRP_CAP * 4;
    int2* nodeInfo = (int2*)ws;  ws += (size_t)NN * 8;
    float* dinv = (float*)ws;    ws += (size_t)NN * 4;
    int* bucketCnt = (int*)ws;   ws += 256 * 4;
    int* bucketOff = (int*)ws;   ws += 256 * 4;
    int* bucketCur = (int*)ws;   ws += 256 * 4;
    u16* Wt = (u16*)ws;          ws += (size_t)6 * 65536 * 2;
    u16* xt = (u16*)ws;          ws += (size_t)NT * 256 * 2;
    u16* ht = (u16*)ws;          ws += (size_t)NT * 256 * 2;

    const int* e_src = edges;
    const int* e_dst = edges + NE;

    k_wt<<<1536, 256, 0, stream>>>(gnn_W, lin_W, Wt);
    k_zero<<<1, 256, 0, stream>>>(bucketCnt, NBUCK);
    k_binA<<<782, 256, 0, stream>>>(e_dst, bucketCnt);
    k_bscan<<<1, 256, 0, stream>>>(bucketCnt, bucketOff, bucketCur);
    k_binB<<<782, 256, 0, stream>>>(e_src, e_dst, bucketCur, recs);
    k_csrA<<<NBUCK, 256, 0, stream>>>(recs, bucketOff, nodeInfo, dinv, csrp);
    k_csrB<<<NBUCK, 256, 0, stream>>>(recs, bucketOff, nodeInfo, dinv, csrp);

    for (int l = 0; l < 4; l++) {
        if (l == 0)
            k_gemm_emb<<<dim3(782, 2), 256, 0, stream>>>(tokens, emb,
                                                         Wt, h, NN);
        else
            k_gemm<<<dim3(782, 2), 256, 0, stream>>>(x, Wt + l * 65536, h, NN);
        k_aggr<<<25000, 256, 0, stream>>>(h, nodeInfo, csrp,
                                          gnn_b + l * 256, gnn_g + l * 256,
                                          gnn_be + l * 256, x);
    }
    k_gather<<<2048, 256, 0, stream>>>(x, tgt, xt);
    for (int l = 0; l < 2; l++) {
        k_gemm<<<dim3(64, 2), 256, 0, stream>>>(xt, Wt + (4 + l) * 65536, ht, NT);
        k_lnrelu<<<2048, 256, 0, stream>>>(ht, lin_b + l * 256, lin_g + l * 256,
                                           lin_be + l * 256, xt);
    }
    k_out<<<2048, 256, 0, stream>>>(xt, out_W, out_b, out);
}

// Round 11
// 1293.189 us; speedup vs baseline: 1.3426x; 1.0216x over previous
//
#include <hip/hip_runtime.h>
#include <hip/hip_fp16.h>

#define NN 100000
#define NE 3200000
#define DD 256
#define NT 8192
#define NOUT 10
#define NBUCK 196        // ceil(100000/512) buckets of 512 dst nodes
// per bucket: edges + 512 self + <=512*7 pad + 8 align slack
#define CSRP_CAP (NE + NBUCK * 4112 + 64)

typedef unsigned short u16;
typedef unsigned int u32;
typedef __attribute__((ext_vector_type(8))) short bf16x8;
typedef __attribute__((ext_vector_type(4))) float f32x4;

__device__ __forceinline__ float bf2f(u16 u) {
    union { unsigned int i; float f; } v; v.i = ((unsigned int)u) << 16; return v.f;
}
__device__ __forceinline__ u16 f2bf(float f) {
    union { float f; unsigned int i; } v; v.f = f;
    unsigned int x = v.i;
    return (u16)((x + 0x7fffu + ((x >> 16) & 1u)) >> 16);
}
__device__ __forceinline__ unsigned int pack2(float a, float b) {
    return (unsigned int)f2bf(a) | ((unsigned int)f2bf(b) << 16);
}
// pack src(17b) | fp16-no-sign(15b); w>0 always
__device__ __forceinline__ u32 packrec(int src, float w) {
    unsigned short h = __half_as_ushort(__float2half(w));
    return ((u32)src << 15) | (u32)(h & 0x7fff);
}
__device__ __forceinline__ float recw(u32 r) {
    return __half2float(__ushort_as_half((unsigned short)(r & 0x7fff)));
}

#define UNPK(u, lo, hi) { union{unsigned int i; float f;} _x,_y; \
    _x.i=(u)<<16; _y.i=(u)&0xffff0000u; lo=_x.f; hi=_y.f; }

__device__ __forceinline__ void gl2lds16(const void* g, void* l) {
    __builtin_amdgcn_global_load_lds(
        (const __attribute__((address_space(1))) unsigned int*)g,
        (__attribute__((address_space(3))) unsigned int*)l, 16, 0, 0);
}

// ---- weight convert + transpose: Wt[l][n][k] = bf16(W[l][k][n]) ----
// block 0 also zeroes bucketCnt (saves a dispatch)
__global__ __launch_bounds__(256) void k_wt(const float* __restrict__ gW,
                                            const float* __restrict__ lW,
                                            u16* __restrict__ Wt,
                                            int* __restrict__ bucketCnt) {
    if (blockIdx.x == 0 && threadIdx.x < NBUCK) bucketCnt[threadIdx.x] = 0;
    int idx = blockIdx.x * 256 + threadIdx.x;      // < 6*65536
    int l = idx >> 16;
    int nk = idx & 65535;
    int n = nk >> 8, k = nk & 255;
    float v = (l < 4) ? gW[l * 65536 + k * 256 + n]
                      : lW[(l - 4) * 65536 + k * 256 + n];
    Wt[idx] = f2bf(v);
}

// ---- pass A: per-bucket edge counts ----
__global__ __launch_bounds__(256) void k_binA(const int* __restrict__ dst,
                                              int* __restrict__ bucketCnt) {
    __shared__ int hist[NBUCK];
    int t = threadIdx.x;
    if (t < NBUCK) hist[t] = 0;
    __syncthreads();
    int base = blockIdx.x * 4096;
#pragma unroll
    for (int i = 0; i < 16; i++) {
        int e = base + i * 256 + t;
        if (e < NE) atomicAdd(&hist[dst[e] >> 9], 1);
    }
    __syncthreads();
    if (t < NBUCK && hist[t] > 0) atomicAdd(&bucketCnt[t], hist[t]);
}

// ---- scan bucket counts -> bucketOff (stable) + bucketCur (cursor) ----
__global__ __launch_bounds__(256) void k_bscan(const int* __restrict__ bucketCnt,
                                               int* __restrict__ bucketOff,
                                               int* __restrict__ bucketCur) {
    __shared__ int s[256];
    int t = threadIdx.x;
    int v = (t < NBUCK) ? bucketCnt[t] : 0;
    s[t] = v;
    __syncthreads();
    for (int o = 1; o < 256; o <<= 1) {
        int a = (t >= o) ? s[t - o] : 0;
        __syncthreads();
        s[t] += a;
        __syncthreads();
    }
    if (t < NBUCK) {
        int ex = s[t] - v;
        bucketOff[t] = ex;
        bucketCur[t] = ex;
    }
    if (t == 0) bucketOff[NBUCK] = NE;
}

// ---- pass B: write records at ABSOLUTE bucket offsets ----
// 1024 threads x 16 edges => ~84-record (336 B) runs per (block,bucket):
// 4x longer contiguous writes than the 256-thread version (less write ampl.)
// record = (src << 9) | (dst & 511)   (src < 2^17)
__global__ __launch_bounds__(1024) void k_binB(const int* __restrict__ src,
                                               const int* __restrict__ dst,
                                               int* __restrict__ bucketCur,
                                               int* __restrict__ recs) {
    __shared__ int hist[NBUCK];
    __shared__ int gbase[NBUCK];
    int t = threadIdx.x;
    if (t < NBUCK) hist[t] = 0;
    __syncthreads();
    int base = blockIdx.x * 16384;
    int recv[16], bks[16], rnk[16];
#pragma unroll
    for (int i = 0; i < 16; i++) {
        int e = base + i * 1024 + t;
        int bk = -1, rec = 0;
        if (e < NE) {
            int s_ = src[e], d_ = dst[e];
            bk = d_ >> 9;
            rec = (s_ << 9) | (d_ & 511);
        }
        bks[i] = bk; recv[i] = rec;
    }
#pragma unroll
    for (int i = 0; i < 16; i++)
        rnk[i] = (bks[i] >= 0) ? atomicAdd(&hist[bks[i]], 1) : 0;
    __syncthreads();
    if (t < NBUCK) {
        int c = hist[t];
        gbase[t] = (c > 0) ? atomicAdd(&bucketCur[t], c) : 0;  // absolute
    }
    __syncthreads();
#pragma unroll
    for (int i = 0; i < 16; i++)
        if (bks[i] >= 0) {
            int pos = gbase[bks[i]] + rnk[i];
            pos = min(max(pos, 0), NE - 1);
            recs[pos] = recv[i];
        }
}

// ---- csrA: per-bucket count + padded scan -> nodeInfo/dinv/self/dummies ----
// csrp record = u32 (src<<15)|fp16w; per node: [self][edges...][dummies] pad 8
// NOTE: must be a SEPARATE dispatch from csrB — csrB reads dinv[s] for
// arbitrary s (cross-bucket); merging creates a cross-workgroup RAW race (R9).
__global__ __launch_bounds__(256) void k_csrA(const int* __restrict__ recs,
                                              const int* __restrict__ bucketOff,
                                              int2* __restrict__ nodeInfo,
                                              float* __restrict__ dinv,
                                              u32* __restrict__ csrp) {
    __shared__ int cnt[512], off[512];
    int b = blockIdx.x, t = threadIdx.x;
    int beg = min(max(bucketOff[b], 0), NE);
    int end = min(max(bucketOff[b + 1], beg), NE);
    int n = end - beg;
    cnt[t] = 0; cnt[t + 256] = 0;
    __syncthreads();
    for (int i = t; i < n; i += 256)
        atomicAdd(&cnt[recs[beg + i] & 511], 1);
    __syncthreads();
    off[t] = (cnt[t] + 8) & ~7;            // padded size: cnt+1 self, round to 8
    off[t + 256] = (cnt[t + 256] + 8) & ~7;
    __syncthreads();
    for (int o = 1; o < 512; o <<= 1) {
        int v0 = (t >= o) ? off[t - o] : 0;
        int v1 = (t + 256 >= o) ? off[t + 256 - o] : 0;
        __syncthreads();
        off[t] += v0; off[t + 256] += v1;
        __syncthreads();
    }
    int base = (beg + b * 4112 + 7) & ~7;  // 8-record aligned bucket region
    for (int k = t; k < 512; k += 256) {
        int node = b * 512 + k;
        if (node >= NN) continue;
        int pd = (cnt[k] + 8) & ~7;
        int nbeg = base + off[k] - pd;     // exclusive padded scan (8-aligned)
        int2 ni; ni.x = nbeg; ni.y = pd;
        nodeInfo[node] = ni;
        float di = rsqrtf((float)(cnt[k] + 1));
        dinv[node] = di;
        csrp[nbeg] = packrec(node, di * di);
        for (int j = nbeg + 1 + cnt[k]; j < nbeg + pd; j++) csrp[j] = 0u;
    }
}

// ---- csrB: scatter edges with precomputed fp16 weight ----
__global__ __launch_bounds__(256) void k_csrB(const int* __restrict__ recs,
                                              const int* __restrict__ bucketOff,
                                              const int2* __restrict__ nodeInfo,
                                              const float* __restrict__ dinv,
                                              u32* __restrict__ csrp) {
    __shared__ int cur[512];
    int b = blockIdx.x, t = threadIdx.x;
    cur[t] = 0; cur[t + 256] = 0;
    __syncthreads();
    int beg = min(max(bucketOff[b], 0), NE);
    int end = min(max(bucketOff[b + 1], beg), NE);
    int n = end - beg;
    for (int i = t; i < n; i += 256) {
        int r = recs[beg + i];
        int dlow = r & 511;
        int s = min(max(r >> 9, 0), NN - 1);
        int node = b * 512 + dlow;
        int rk = atomicAdd(&cur[dlow], 1);
        int2 ni = nodeInfo[node];
        float w = dinv[s] * dinv[node];
        int pos = ni.x + 1 + rk;
        pos = min(max(pos, 0), CSRP_CAP - 1);
        csrp[pos] = packrec(s, w);
    }
}

// ---- shared GEMM epilogue ----
#define GEMM_EPILOGUE                                                         \
    for (int i = 0; i < 4; i++)                                               \
        for (int j = 0; j < 4; j++) {                                         \
            int col = colBase + wn * 64 + j * 16 + l16;                       \
            for (int r = 0; r < 4; r++) {                                     \
                int row = rowBase + wm * 64 + i * 16 + quad * 4 + r;          \
                if (row < M) C[row * 256 + col] = f2bf(acc[i][j][r]);         \
            }                                                                 \
        }

#define GEMM_COMPUTE(ASRC, BSRC)                                              \
    for (int ks = 0; ks < 2; ks++) {                                          \
        bf16x8 a_frag[4], b_frag[4];                                          \
        for (int i = 0; i < 4; i++) {                                         \
            int r = wm * 64 + i * 16 + l16;                                   \
            int ch = (ks * 4 + quad) ^ (r & 7);                               \
            a_frag[i] = *(const bf16x8*)(&ASRC[r * 64 + ch * 8]);             \
        }                                                                     \
        for (int j = 0; j < 4; j++) {                                         \
            int r = wn * 64 + j * 16 + l16;                                   \
            int ch = (ks * 4 + quad) ^ (r & 7);                               \
            b_frag[j] = *(const bf16x8*)(&BSRC[r * 64 + ch * 8]);             \
        }                                                                     \
        for (int i = 0; i < 4; i++)                                           \
            for (int j = 0; j < 4; j++)                                       \
                acc[i][j] = __builtin_amdgcn_mfma_f32_16x16x32_bf16(          \
                    a_frag[i], b_frag[j], acc[i][j], 0, 0, 0);                \
    }

// ---- bf16 MFMA GEMM, BK=64 single-buffered, global_load_lds staging ----
// C[M,256] = A[M,256] @ Bt^T   (Bt is [256 n][256 k]); 32 KB LDS -> ~5 blk/CU
__global__ __launch_bounds__(256) void k_gemm(const u16* __restrict__ A,
                                              const u16* __restrict__ Bt,
                                              u16* __restrict__ C, int M) {
    __shared__ __align__(16) u16 As[128 * 64];
    __shared__ __align__(16) u16 Bs[128 * 64];
    const int tid = threadIdx.x;
    const int wave = tid >> 6, lane = tid & 63;
    const int wm = wave >> 1, wn = wave & 1;
    const int rowBase = blockIdx.x * 128;
    const int colBase = blockIdx.y * 128;
    const int quad = lane >> 4, l16 = lane & 15;

    f32x4 acc[4][4] = {};

    for (int kk = 0; kk < 4; kk++) {
        int k0 = kk * 64;
#pragma unroll
        for (int i = 0; i < 4; i++) {
            int j = (i * 4 + wave) * 64 + lane;    // task 0..1023
            int r = j >> 3, c = j & 7;
            int cg = c ^ (r & 7);                  // source-chunk swizzle
            int ga = rowBase + r; if (ga >= M) ga = M - 1;
            gl2lds16(A + (size_t)ga * 256 + k0 + cg * 8,
                     &As[(i * 4 + wave) * 512]);
            gl2lds16(Bt + (size_t)(colBase + r) * 256 + k0 + cg * 8,
                     &Bs[(i * 4 + wave) * 512]);
        }
        __syncthreads();
        GEMM_COMPUTE(As, Bs)
        __syncthreads();
    }
    GEMM_EPILOGUE
}

// ---- GEMM-1: A rows gathered from f32 embedding table (embed fused) ----
__global__ __launch_bounds__(256) void k_gemm_emb(const int* __restrict__ tokens,
                                                  const float* __restrict__ emb,
                                                  const u16* __restrict__ Bt,
                                                  u16* __restrict__ C, int M) {
    __shared__ __align__(16) u16 As[128 * 64];
    __shared__ __align__(16) u16 Bs[128 * 64];
    __shared__ int tokLDS[128];
    const int tid = threadIdx.x;
    const int wave = tid >> 6, lane = tid & 63;
    const int wm = wave >> 1, wn = wave & 1;
    const int rowBase = blockIdx.x * 128;
    const int colBase = blockIdx.y * 128;
    const int quad = lane >> 4, l16 = lane & 15;

    if (tid < 128) {
        int ga = rowBase + tid; if (ga >= M) ga = M - 1;
        tokLDS[tid] = tokens[ga];
    }
    f32x4 acc[4][4] = {};
    __syncthreads();

    for (int kk = 0; kk < 4; kk++) {
        int k0 = kk * 64;
#pragma unroll
        for (int i = 0; i < 4; i++) {
            int j = (i * 4 + wave) * 64 + lane;    // task 0..1023
            int r = j >> 3, c = j & 7;
            int cg = c ^ (r & 7);
            // A: gather f32 embedding row, convert to bf16, LDS write 16B
            const float* srcp = emb + (size_t)tokLDS[r] * 256 + k0 + cg * 8;
            float4 f0 = *(const float4*)srcp;
            float4 f1 = *(const float4*)(srcp + 4);
            uint4 pk;
            pk.x = pack2(f0.x, f0.y); pk.y = pack2(f0.z, f0.w);
            pk.z = pack2(f1.x, f1.y); pk.w = pack2(f1.z, f1.w);
            *(uint4*)(&As[j * 8]) = pk;
            // B: weights via global_load_lds
            gl2lds16(Bt + (size_t)(colBase + r) * 256 + k0 + cg * 8,
                     &Bs[(i * 4 + wave) * 512]);
        }
        __syncthreads();
        GEMM_COMPUTE(As, Bs)
        __syncthreads();
    }
    GEMM_EPILOGUE
}

// ---- lin GEMM-1: A rows gathered from x via tgt (k_gather fused) ----
__global__ __launch_bounds__(256) void k_gemm_gather(const u16* __restrict__ X,
                                                     const int* __restrict__ tgt,
                                                     const u16* __restrict__ Bt,
                                                     u16* __restrict__ C, int M) {
    __shared__ __align__(16) u16 As[128 * 64];
    __shared__ __align__(16) u16 Bs[128 * 64];
    __shared__ int rowLDS[128];
    const int tid = threadIdx.x;
    const int wave = tid >> 6, lane = tid & 63;
    const int wm = wave >> 1, wn = wave & 1;
    const int rowBase = blockIdx.x * 128;
    const int colBase = blockIdx.y * 128;
    const int quad = lane >> 4, l16 = lane & 15;

    if (tid < 128) {
        int ga = rowBase + tid; if (ga >= M) ga = M - 1;
        rowLDS[tid] = tgt[ga];
    }
    f32x4 acc[4][4] = {};
    __syncthreads();

    for (int kk = 0; kk < 4; kk++) {
        int k0 = kk * 64;
#pragma unroll
        for (int i = 0; i < 4; i++) {
            int j = (i * 4 + wave) * 64 + lane;    // task 0..1023
            int r = j >> 3, c = j & 7;
            int cg = c ^ (r & 7);
            uint4 v = *(const uint4*)(X + (size_t)rowLDS[r] * 256 + k0 + cg * 8);
            *(uint4*)(&As[j * 8]) = v;
            gl2lds16(Bt + (size_t)(colBase + r) * 256 + k0 + cg * 8,
                     &Bs[(i * 4 + wave) * 512]);
        }
        __syncthreads();
        GEMM_COMPUTE(As, Bs)
        __syncthreads();
    }
    GEMM_EPILOGUE
}

// ---- fused aggregate + bias + LN + ReLU (padded CSR, packed u32 recs) ----
__global__ __launch_bounds__(256) void k_aggr(const u16* __restrict__ h,
                                              const int2* __restrict__ nodeInfo,
                                              const u32* __restrict__ csrp,
                                              const float* __restrict__ bias,
                                              const float* __restrict__ gamma,
                                              const float* __restrict__ beta,
                                              u16* __restrict__ xo) {
    const int wave = threadIdx.x >> 6, lane = threadIdx.x & 63;
    const int half = lane >> 5, l32 = lane & 31;
    const int node = blockIdx.x * 4 + wave;
    const int d8 = l32 * 8;                  // 8 dims per lane
    int2 ni = nodeInfo[node];
    float a0=0,a1=0,a2=0,a3=0,a4=0,a5=0,a6=0,a7=0;
    const u32* cp = csrp + ni.x + half * 4;
    for (int j = 0; j < ni.y; j += 8, cp += 8) {
        uint4 rr = *(const uint4*)cp;        // 4 packed records
        int s0 = rr.x >> 15, s1 = rr.y >> 15, s2 = rr.z >> 15, s3 = rr.w >> 15;
        uint4 v0 = *(const uint4*)(h + s0 * 256 + d8);
        uint4 v1 = *(const uint4*)(h + s1 * 256 + d8);
        uint4 v2 = *(const uint4*)(h + s2 * 256 + d8);
        uint4 v3 = *(const uint4*)(h + s3 * 256 + d8);
        float w0 = recw(rr.x), w1 = recw(rr.y), w2 = recw(rr.z), w3 = recw(rr.w);
        float p,q;
        UNPK(v0.x,p,q); a0=fmaf(w0,p,a0); a1=fmaf(w0,q,a1);
        UNPK(v0.y,p,q); a2=fmaf(w0,p,a2); a3=fmaf(w0,q,a3);
        UNPK(v0.z,p,q); a4=fmaf(w0,p,a4); a5=fmaf(w0,q,a5);
        UNPK(v0.w,p,q); a6=fmaf(w0,p,a6); a7=fmaf(w0,q,a7);
        UNPK(v1.x,p,q); a0=fmaf(w1,p,a0); a1=fmaf(w1,q,a1);
        UNPK(v1.y,p,q); a2=fmaf(w1,p,a2); a3=fmaf(w1,q,a3);
        UNPK(v1.z,p,q); a4=fmaf(w1,p,a4); a5=fmaf(w1,q,a5);
        UNPK(v1.w,p,q); a6=fmaf(w1,p,a6); a7=fmaf(w1,q,a7);
        UNPK(v2.x,p,q); a0=fmaf(w2,p,a0); a1=fmaf(w2,q,a1);
        UNPK(v2.y,p,q); a2=fmaf(w2,p,a2); a3=fmaf(w2,q,a3);
        UNPK(v2.z,p,q); a4=fmaf(w2,p,a4); a5=fmaf(w2,q,a5);
        UNPK(v2.w,p,q); a6=fmaf(w2,p,a6); a7=fmaf(w2,q,a7);
        UNPK(v3.x,p,q); a0=fmaf(w3,p,a0); a1=fmaf(w3,q,a1);
        UNPK(v3.y,p,q); a2=fmaf(w3,p,a2); a3=fmaf(w3,q,a3);
        UNPK(v3.z,p,q); a4=fmaf(w3,p,a4); a5=fmaf(w3,q,a5);
        UNPK(v3.w,p,q); a6=fmaf(w3,p,a6); a7=fmaf(w3,q,a7);
    }
    a0 += __shfl_xor(a0, 32, 64); a1 += __shfl_xor(a1, 32, 64);
    a2 += __shfl_xor(a2, 32, 64); a3 += __shfl_xor(a3, 32, 64);
    a4 += __shfl_xor(a4, 32, 64); a5 += __shfl_xor(a5, 32, 64);
    a6 += __shfl_xor(a6, 32, 64); a7 += __shfl_xor(a7, 32, 64);

    float4 b0 = *(const float4*)(bias + d8);
    float4 b1 = *(const float4*)(bias + d8 + 4);
    a0 += b0.x; a1 += b0.y; a2 += b0.z; a3 += b0.w;
    a4 += b1.x; a5 += b1.y; a6 += b1.z; a7 += b1.w;
    float s1 = a0+a1+a2+a3+a4+a5+a6+a7;
    float s2 = a0*a0+a1*a1+a2*a2+a3*a3+a4*a4+a5*a5+a6*a6+a7*a7;
    for (int o = 16; o >= 1; o >>= 1) {
        s1 += __shfl_xor(s1, o, 64);
        s2 += __shfl_xor(s2, o, 64);
    }
    float mean = s1 * (1.0f / 256.0f);
    float var = s2 * (1.0f / 256.0f) - mean * mean;
    float rstd = rsqrtf(var + 1e-5f);
    if (half == 0) {
        float4 g0 = *(const float4*)(gamma + d8);
        float4 g1 = *(const float4*)(gamma + d8 + 4);
        float4 e0 = *(const float4*)(beta + d8);
        float4 e1 = *(const float4*)(beta + d8 + 4);
        float y0 = fmaxf((a0 - mean) * rstd * g0.x + e0.x, 0.0f);
        float y1 = fmaxf((a1 - mean) * rstd * g0.y + e0.y, 0.0f);
        float y2 = fmaxf((a2 - mean) * rstd * g0.z + e0.z, 0.0f);
        float y3 = fmaxf((a3 - mean) * rstd * g0.w + e0.w, 0.0f);
        float y4 = fmaxf((a4 - mean) * rstd * g1.x + e1.x, 0.0f);
        float y5 = fmaxf((a5 - mean) * rstd * g1.y + e1.y, 0.0f);
        float y6 = fmaxf((a6 - mean) * rstd * g1.z + e1.z, 0.0f);
        float y7 = fmaxf((a7 - mean) * rstd * g1.w + e1.w, 0.0f);
        uint4 o;
        o.x = pack2(y0, y1);
        o.y = pack2(y2, y3);
        o.z = pack2(y4, y5);
        o.w = pack2(y6, y7);
        *(uint4*)(xo + node * 256 + d8) = o;
    }
}

__global__ __launch_bounds__(256) void k_lnrelu(const u16* __restrict__ h,
                                                const float* __restrict__ bias,
                                                const float* __restrict__ gamma,
                                                const float* __restrict__ beta,
                                                u16* __restrict__ xo) {
    int wave = threadIdx.x >> 6, lane = threadIdx.x & 63;
    int row = blockIdx.x * 4 + wave;
    int base = row * 256 + lane * 4;
    ushort4 hv = *(const ushort4*)(h + base);
    float4 bv = *(const float4*)(bias + lane * 4);
    float a0 = bf2f(hv.x) + bv.x, a1 = bf2f(hv.y) + bv.y;
    float a2 = bf2f(hv.z) + bv.z, a3 = bf2f(hv.w) + bv.w;
    float s1 = a0 + a1 + a2 + a3;
    float s2 = a0 * a0 + a1 * a1 + a2 * a2 + a3 * a3;
    for (int o = 32; o >= 1; o >>= 1) {
        s1 += __shfl_xor(s1, o, 64);
        s2 += __shfl_xor(s2, o, 64);
    }
    float mean = s1 * (1.0f / 256.0f);
    float var = s2 * (1.0f / 256.0f) - mean * mean;
    float rstd = rsqrtf(var + 1e-5f);
    float4 gv = *(const float4*)(gamma + lane * 4);
    float4 be = *(const float4*)(beta + lane * 4);
    float y0 = fmaxf((a0 - mean) * rstd * gv.x + be.x, 0.0f);
    float y1 = fmaxf((a1 - mean) * rstd * gv.y + be.y, 0.0f);
    float y2 = fmaxf((a2 - mean) * rstd * gv.z + be.z, 0.0f);
    float y3 = fmaxf((a3 - mean) * rstd * gv.w + be.w, 0.0f);
    ushort4 o4;
    o4.x = f2bf(y0); o4.y = f2bf(y1); o4.z = f2bf(y2); o4.w = f2bf(y3);
    *(ushort4*)(xo + base) = o4;
}

// ---- last layer: bias + LN + ReLU + [256x10] out-proj fused ----
__global__ __launch_bounds__(256) void k_lnout(const u16* __restrict__ h,
                                               const float* __restrict__ bias,
                                               const float* __restrict__ gamma,
                                               const float* __restrict__ beta,
                                               const float* __restrict__ W,
                                               const float* __restrict__ ob,
                                               float* __restrict__ out) {
    __shared__ float Ws[DD * NOUT];
    int tid = threadIdx.x;
    for (int i = tid; i < DD * NOUT; i += 256) Ws[i] = W[i];
    __syncthreads();
    int wave = tid >> 6, lane = tid & 63;
    int row = blockIdx.x * 4 + wave;
    int base = row * 256 + lane * 4;
    ushort4 hv = *(const ushort4*)(h + base);
    float4 bv = *(const float4*)(bias + lane * 4);
    float a0 = bf2f(hv.x) + bv.x, a1 = bf2f(hv.y) + bv.y;
    float a2 = bf2f(hv.z) + bv.z, a3 = bf2f(hv.w) + bv.w;
    float s1 = a0 + a1 + a2 + a3;
    float s2 = a0 * a0 + a1 * a1 + a2 * a2 + a3 * a3;
    for (int o = 32; o >= 1; o >>= 1) {
        s1 += __shfl_xor(s1, o, 64);
        s2 += __shfl_xor(s2, o, 64);
    }
    float mean = s1 * (1.0f / 256.0f);
    float var = s2 * (1.0f / 256.0f) - mean * mean;
    float rstd = rsqrtf(var + 1e-5f);
    float4 gv = *(const float4*)(gamma + lane * 4);
    float4 be = *(const float4*)(beta + lane * 4);
    // match reference numerics: y = bf16(relu(...)) then matmul
    float y0 = bf2f(f2bf(fmaxf((a0 - mean) * rstd * gv.x + be.x, 0.0f)));
    float y1 = bf2f(f2bf(fmaxf((a1 - mean) * rstd * gv.y + be.y, 0.0f)));
    float y2 = bf2f(f2bf(fmaxf((a2 - mean) * rstd * gv.z + be.z, 0.0f)));
    float y3 = bf2f(f2bf(fmaxf((a3 - mean) * rstd * gv.w + be.w, 0.0f)));
    int d = lane * 4;
    for (int o = 0; o < NOUT; o++) {
        float p = y0 * Ws[(d + 0) * NOUT + o] + y1 * Ws[(d + 1) * NOUT + o] +
                  y2 * Ws[(d + 2) * NOUT + o] + y3 * Ws[(d + 3) * NOUT + o];
        for (int off = 32; off >= 1; off >>= 1) p += __shfl_xor(p, off, 64);
        if (lane == 0) out[row * NOUT + o] = p + ob[o];
    }
}

extern "C" void kernel_launch(void* const* d_in, const int* in_sizes, int n_in,
                              void* d_out, int out_size, void* d_ws, size_t ws_size,
                              hipStream_t stream) {
    (void)in_sizes; (void)n_in; (void)out_size; (void)ws_size;
    const int* tokens = (const int*)d_in[0];
    const int* edges = (const int*)d_in[1];
    const int* tgt = (const int*)d_in[2];
    const float* emb = (const float*)d_in[3];
    const float* gnn_W = (const float*)d_in[4];
    const float* gnn_b = (const float*)d_in[5];
    const float* gnn_g = (const float*)d_in[6];
    const float* gnn_be = (const float*)d_in[7];
    const float* lin_W = (const float*)d_in[8];
    const float* lin_b = (const float*)d_in[9];
    const float* lin_g = (const float*)d_in[10];
    const float* lin_be = (const float*)d_in[11];
    const float* out_W = (const float*)d_in[12];
    const float* out_b = (const float*)d_in[13];
    float* out = (float*)d_out;

    char* ws = (char*)d_ws;
    u16* x = (u16*)ws;           ws += (size_t)NN * 256 * 2;
    // h aliases recs: recs dead before first GEMM writes h
    char* hreg = ws;             ws += (size_t)NN * 256 * 2;
    u16* h = (u16*)hreg;
    int* recs = (int*)hreg;      // NE*4 = 12.8MB < 51.2MB
    u32* csrp = (u32*)ws;        ws += (size_t)CSRP_CAP * 4;
    int2* nodeInfo = (int2*)ws;  ws += (size_t)NN * 8;
    float* dinv = (float*)ws;    ws += (size_t)NN * 4;
    int* bucketCnt = (int*)ws;   ws += 256 * 4;
    int* bucketOff = (int*)ws;   ws += 256 * 4;
    int* bucketCur = (int*)ws;   ws += 256 * 4;
    u16* Wt = (u16*)ws;          ws += (size_t)6 * 65536 * 2;
    u16* xt = (u16*)ws;          ws += (size_t)NT * 256 * 2;
    u16* ht = (u16*)ws;          ws += (size_t)NT * 256 * 2;

    const int* e_src = edges;
    const int* e_dst = edges + NE;

    k_wt<<<1536, 256, 0, stream>>>(gnn_W, lin_W, Wt, bucketCnt);
    k_binA<<<782, 256, 0, stream>>>(e_dst, bucketCnt);
    k_bscan<<<1, 256, 0, stream>>>(bucketCnt, bucketOff, bucketCur);
    k_binB<<<196, 1024, 0, stream>>>(e_src, e_dst, bucketCur, recs);
    k_csrA<<<NBUCK, 256, 0, stream>>>(recs, bucketOff, nodeInfo, dinv, csrp);
    k_csrB<<<NBUCK, 256, 0, stream>>>(recs, bucketOff, nodeInfo, dinv, csrp);

    for (int l = 0; l < 4; l++) {
        if (l == 0)
            k_gemm_emb<<<dim3(782, 2), 256, 0, stream>>>(tokens, emb,
                                                         Wt, h, NN);
        else
            k_gemm<<<dim3(782, 2), 256, 0, stream>>>(x, Wt + l * 65536, h, NN);
        k_aggr<<<25000, 256, 0, stream>>>(h, nodeInfo, csrp,
                                          gnn_b + l * 256, gnn_g + l * 256,
                                          gnn_be + l * 256, x);
    }
    // lin layer 0: gather fused into GEMM A-staging
    k_gemm_gather<<<dim3(64, 2), 256, 0, stream>>>(x, tgt, Wt + 4 * 65536,
                                                   ht, NT);
    k_lnrelu<<<2048, 256, 0, stream>>>(ht, lin_b, lin_g, lin_be, xt);
    // lin layer 1: GEMM then LN+ReLU+out-proj fused
    k_gemm<<<dim3(64, 2), 256, 0, stream>>>(xt, Wt + 5 * 65536, ht, NT);
    k_lnout<<<2048, 256, 0, stream>>>(ht, lin_b + 256, lin_g + 256,
                                      lin_be + 256, out_W, out_b, out);
}